// Round 1
// baseline (2401.005 us; speedup 1.0000x reference)
//
#include <hip/hip_runtime.h>

// Laplacian pyramid loss, 3 levels, B*C = 48 channels of 512x512 f32.
// Level L: H = 512>>L.  down = decimate(gauss5x5_reflect(cur)).
// diff = cur - conv5x5(zero-interleave(down), 4*gk) with reflect pad.
// miniloss (size H+2): |conv3x3(diff,gx)| + |conv3x3(diff,gy)|, reflect pad 2.
// loss += mean(|miniloss_in - miniloss_tg|).

#define NCH 48

__device__ __forceinline__ int refl(int p, int n) {
  // jnp.pad mode='reflect' (no edge repeat), pad <= 2, n >= 4
  return p < 0 ? -p : (p >= n ? 2 * n - 2 - p : p);
}

__global__ void gauss_down_kernel(const float* __restrict__ cur, float* __restrict__ down,
                                  const float* __restrict__ gk, int H, int W)
{
  __shared__ float sgk[25];
  int tid = threadIdx.x;
  if (tid < 25) sgk[tid] = gk[tid];
  __syncthreads();
  int n = blockIdx.z;
  int h = blockIdx.y;
  int w = blockIdx.x * blockDim.x + tid;
  int H2 = H >> 1, W2 = W >> 1;
  if (w >= W2) return;
  float s = 0.f;
#pragma unroll
  for (int i = 0; i < 5; ++i) {
    int p = refl(2 * h + i - 2, H);
    const float* row = cur + ((size_t)n * H + p) * W;
#pragma unroll
    for (int j = 0; j < 5; ++j) {
      int q = refl(2 * w + j - 2, W);
      s += sgk[i * 5 + j] * row[q];
    }
  }
  down[((size_t)n * H2 + h) * W2 + w] = s;
}

// diff(p,q) = cur(p,q) - up(p,q);  (p,q) already reflected into [0,H)x[0,W)
__device__ __forceinline__ float diff_at(const float* __restrict__ cur,
                                         const float* __restrict__ down,
                                         const float* sgk4, int n, int p, int q,
                                         int H, int W)
{
  int H2 = H >> 1, W2 = W >> 1;
  float up = 0.f;
#pragma unroll
  for (int i = 0; i < 5; ++i) {
    int rt = refl(p + i - 2, H);
    if (!(rt & 1)) {
      const float* drow = down + ((size_t)n * H2 + (rt >> 1)) * W2;
#pragma unroll
      for (int j = 0; j < 5; ++j) {
        int rs = refl(q + j - 2, W);
        if (!(rs & 1)) up += sgk4[i * 5 + j] * drow[rs >> 1];
      }
    }
  }
  return cur[((size_t)n * H + p) * W + q] - up;
}

__global__ void lap_loss_kernel(const float* __restrict__ cur_in, const float* __restrict__ cur_tg,
                                const float* __restrict__ down_in, const float* __restrict__ down_tg,
                                const float* __restrict__ gk, int H, int W, float scale,
                                double* __restrict__ acc)
{
  __shared__ float sgk4[25];
  int tid = threadIdx.y * blockDim.x + threadIdx.x;
  if (tid < 25) sgk4[tid] = 4.f * gk[tid];
  __syncthreads();
  int n = blockIdx.z;
  int x = blockIdx.x * blockDim.x + threadIdx.x;
  int y = blockIdx.y * blockDim.y + threadIdx.y;
  int HO = H + 2, WO = W + 2;
  float val = 0.f;
  if (x < WO && y < HO) {
    float din[3][3], dtg[3][3];
#pragma unroll
    for (int i = 0; i < 3; ++i) {
      int p = refl(y + i - 2, H);
#pragma unroll
      for (int j = 0; j < 3; ++j) {
        int q = refl(x + j - 2, W);
        din[i][j] = diff_at(cur_in, down_in, sgk4, n, p, q, H, W);
        dtg[i][j] = diff_at(cur_tg, down_tg, sgk4, n, p, q, H, W);
      }
    }
    float gx_in = 2.f * (din[0][0] - din[0][2]) + 4.f * (din[1][0] - din[1][2]) + 2.f * (din[2][0] - din[2][2]);
    float gy_in = 2.f * din[0][0] + 4.f * din[0][1] + 2.f * din[0][2]
                - 2.f * din[2][0] - 4.f * din[2][1] - 2.f * din[2][2];
    float gx_tg = 2.f * (dtg[0][0] - dtg[0][2]) + 4.f * (dtg[1][0] - dtg[1][2]) + 2.f * (dtg[2][0] - dtg[2][2]);
    float gy_tg = 2.f * dtg[0][0] + 4.f * dtg[0][1] + 2.f * dtg[0][2]
                - 2.f * dtg[2][0] - 4.f * dtg[2][1] - 2.f * dtg[2][2];
    float a = fabsf(gx_in) + fabsf(gy_in);
    float b = fabsf(gx_tg) + fabsf(gy_tg);
    val = fabsf(a - b) * scale;
  }
  // block reduction: 64x4 = 256 threads = 4 waves
#pragma unroll
  for (int off = 32; off > 0; off >>= 1) val += __shfl_down(val, off, 64);
  __shared__ float wpart[4];
  if ((tid & 63) == 0) wpart[tid >> 6] = val;
  __syncthreads();
  if (tid == 0) atomicAdd(acc, (double)(wpart[0] + wpart[1] + wpart[2] + wpart[3]));
}

__global__ void finalize_kernel(const double* __restrict__ acc, float* __restrict__ out)
{
  out[0] = (float)acc[0];
}

extern "C" void kernel_launch(void* const* d_in, const int* in_sizes, int n_in,
                              void* d_out, int out_size, void* d_ws, size_t ws_size,
                              hipStream_t stream) {
  const float* in = (const float*)d_in[0];
  const float* tg = (const float*)d_in[1];
  const float* gk = (const float*)d_in[2];  // first 25 floats = the 5x5 kernel (all channels identical)
  float* out = (float*)d_out;

  // workspace layout: [double acc][down0_in][down0_tg][down1_in][down1_tg][down2_in][down2_tg]
  double* acc = (double*)d_ws;
  float* base = (float*)((char*)d_ws + 16);
  const size_t s0 = (size_t)NCH * 256 * 256;  // 3,145,728
  const size_t s1 = (size_t)NCH * 128 * 128;  //   786,432
  const size_t s2 = (size_t)NCH * 64 * 64;    //   196,608
  float* d0i = base;
  float* d0t = d0i + s0;
  float* d1i = d0t + s0;
  float* d1t = d1i + s1;
  float* d2i = d1t + s1;
  float* d2t = d2i + s2;

  hipMemsetAsync(d_ws, 0, 16, stream);

  dim3 bdown(64, 1, 1);
  dim3 bloss(64, 4, 1);

  // ---- level 0: H = 512 ----
  {
    int H = 512, W = 512, H2 = 256, W2 = 256;
    dim3 gdown((W2 + 63) / 64, H2, NCH);
    gauss_down_kernel<<<gdown, bdown, 0, stream>>>(in, d0i, gk, H, W);
    gauss_down_kernel<<<gdown, bdown, 0, stream>>>(tg, d0t, gk, H, W);
    int HO = H + 2, WO = W + 2;
    dim3 gloss((WO + 63) / 64, (HO + 3) / 4, NCH);
    float scale = 1.f / ((float)NCH * HO * WO);
    lap_loss_kernel<<<gloss, bloss, 0, stream>>>(in, tg, d0i, d0t, gk, H, W, scale, acc);
  }
  // ---- level 1: H = 256 ----
  {
    int H = 256, W = 256, H2 = 128, W2 = 128;
    dim3 gdown((W2 + 63) / 64, H2, NCH);
    gauss_down_kernel<<<gdown, bdown, 0, stream>>>(d0i, d1i, gk, H, W);
    gauss_down_kernel<<<gdown, bdown, 0, stream>>>(d0t, d1t, gk, H, W);
    int HO = H + 2, WO = W + 2;
    dim3 gloss((WO + 63) / 64, (HO + 3) / 4, NCH);
    float scale = 1.f / ((float)NCH * HO * WO);
    lap_loss_kernel<<<gloss, bloss, 0, stream>>>(d0i, d0t, d1i, d1t, gk, H, W, scale, acc);
  }
  // ---- level 2: H = 128 ----
  {
    int H = 128, W = 128, H2 = 64, W2 = 64;
    dim3 gdown((W2 + 63) / 64, H2, NCH);
    gauss_down_kernel<<<gdown, bdown, 0, stream>>>(d1i, d2i, gk, H, W);
    gauss_down_kernel<<<gdown, bdown, 0, stream>>>(d1t, d2t, gk, H, W);
    int HO = H + 2, WO = W + 2;
    dim3 gloss((WO + 63) / 64, (HO + 3) / 4, NCH);
    float scale = 1.f / ((float)NCH * HO * WO);
    lap_loss_kernel<<<gloss, bloss, 0, stream>>>(d1i, d1t, d2i, d2t, gk, H, W, scale, acc);
  }

  finalize_kernel<<<1, 1, 0, stream>>>(acc, out);
}

// Round 2
// 485.917 us; speedup vs baseline: 4.9412x; 4.9412x over previous
//
#include <hip/hip_runtime.h>

// Laplacian pyramid loss, 3 levels, B*C = 48 channels of 512x512 f32.
// gk is the fixed separable Gaussian outer([1,4,6,4,1])^2 / 256 (hardcoded).

#define NCH 48
#define TW 32
#define TH 32
#define DSTR (TW + 4)   // 36: diff LDS row stride (conflict-free)
#define NUMAX 20        // max tmp columns per tile

__device__ __forceinline__ int refl(int p, int n) {
  // jnp reflect pad (no edge repeat), |overshoot| <= 2
  return p < 0 ? -p : (p >= n ? 2 * n - 2 - p : p);
}

// ---------------- downsample: decimate(gauss5x5_reflect(cur)) ----------------
__global__ __launch_bounds__(64) void gauss_down_kernel(
    const float* __restrict__ cur, float* __restrict__ down, int H, int W)
{
  const int n = blockIdx.z;
  const int h = blockIdx.y;
  const int w = blockIdx.x * 64 + threadIdx.x;
  const int H2 = H >> 1, W2 = W >> 1;
  if (w >= W2) return;
  const float gg[5] = {1.f, 4.f, 6.f, 4.f, 1.f};
  float s = 0.f;
#pragma unroll
  for (int i = 0; i < 5; ++i) {
    int p = refl(2 * h + i - 2, H);
    const float* row = cur + ((size_t)n * H + p) * W;
    float r = 0.f;
#pragma unroll
    for (int j = 0; j < 5; ++j) {
      int q = refl(2 * w + j - 2, W);
      r += gg[j] * row[q];
    }
    s += gg[i] * r;
  }
  down[((size_t)n * H2 + h) * W2 + w] = s * (1.f / 256.f);
}

// ---------------- fused: diff tile in LDS -> miniloss -> reduce ----------------
// diff = cur - up(down); up = conv5(zero-interleave(down), 4*gk), reflect on the
// interleaved (size-H) grid. Separable: per-axis weights [1,4,6,4,1]/8;
// even coordinate -> taps {1,6,1}/8 on down, odd -> taps {4,4}/8 = avg.
__global__ __launch_bounds__(256) void lap_loss_tile_kernel(
    const float* __restrict__ cur_in, const float* __restrict__ cur_tg,
    const float* __restrict__ down_in, const float* __restrict__ down_tg,
    int H, int W, float scale, double* __restrict__ acc)
{
  const int HO = H + 2, WO = W + 2;
  const int H2 = H >> 1, W2 = W >> 1;
  const int n = blockIdx.z;
  const int x0 = blockIdx.x * TW, y0 = blockIdx.y * TH;
  const int y_end = min(HO, y0 + TH), x_end = min(WO, x0 + TW);
  const int tid = threadIdx.x;

  // stored (reflected) diff row/col ranges
  int rlo = max(0, y0 - 2);
  if (y_end > H) rlo = min(rlo, 2 * H - 1 - y_end);  // refl of rows >= H
  const int rhi = min(H, y_end);
  const int nrows = rhi - rlo;
  int clo = max(0, x0 - 2);
  if (x_end > W) clo = min(clo, 2 * W - 1 - x_end);
  const int chi = min(W, x_end);
  const int ncols = chi - clo;

  // tmp (vertical up-pass) column range in down coordinates
  const int u0 = (clo >= 2) ? ((clo - 2) >> 1) : 0;
  const int u1 = min(W2 - 1, (chi + 1) >> 1);
  const int NU = u1 - u0 + 1;

  __shared__ float s_tmp[2][TH + 2][NUMAX];
  __shared__ float s_diff[2][TH + 2][DSTR];

  const float* curp[2] = {cur_in, cur_tg};
  const float* dnp[2]  = {down_in, down_tg};

  // ---- phase 1: vertical up-pass into s_tmp ----
  for (int img = 0; img < 2; ++img) {
    const float* dn = dnp[img] + (size_t)n * H2 * W2;
    for (int idx = tid; idx < nrows * NU; idx += 256) {
      const int l = idx / NU, du = idx - l * NU;
      const int p = rlo + l;
      const int u = u0 + du;
      float v;
      if (!(p & 1)) {
        int r0 = refl(p - 2, H) >> 1, r1 = p >> 1, r2 = refl(p + 2, H) >> 1;
        v = (dn[(size_t)r0 * W2 + u] + 6.f * dn[(size_t)r1 * W2 + u]
             + dn[(size_t)r2 * W2 + u]) * 0.125f;
      } else {
        int r0 = (p - 1) >> 1, r1 = refl(p + 1, H) >> 1;
        v = (dn[(size_t)r0 * W2 + u] + dn[(size_t)r1 * W2 + u]) * 0.5f;
      }
      s_tmp[img][l][du] = v;
    }
  }
  __syncthreads();

  // ---- phase 2: horizontal up-pass + cur load -> diff in LDS ----
  for (int img = 0; img < 2; ++img) {
    const float* cp = curp[img] + (size_t)n * H * W;
    for (int idx = tid; idx < nrows * ncols; idx += 256) {
      const int l = idx / ncols, c = idx - l * ncols;
      const int p = rlo + l, q = clo + c;
      float up;
      if (!(q & 1)) {
        int uA = refl(q - 2, W) >> 1, uB = q >> 1, uC = refl(q + 2, W) >> 1;
        up = (s_tmp[img][l][uA - u0] + 6.f * s_tmp[img][l][uB - u0]
              + s_tmp[img][l][uC - u0]) * 0.125f;
      } else {
        int uA = (q - 1) >> 1, uB = refl(q + 1, W) >> 1;
        up = (s_tmp[img][l][uA - u0] + s_tmp[img][l][uB - u0]) * 0.5f;
      }
      s_diff[img][l][c] = cp[(size_t)p * W + q] - up;
    }
  }
  __syncthreads();

  // ---- phase 3: 3x3 |gx|+|gy| miniloss, |in - tg|, reduce ----
  float val = 0.f;
  const int tx = tid & 31, ty = tid >> 5;
  const int xx = x0 + tx;
  if (xx < x_end) {
    int cj[3];
#pragma unroll
    for (int j = 0; j < 3; ++j) cj[j] = refl(xx + j - 2, W) - clo;
    for (int yy = y0 + ty; yy < y_end; yy += 8) {
      int li[3];
#pragma unroll
      for (int i = 0; i < 3; ++i) li[i] = refl(yy + i - 2, H) - rlo;
      float ab[2];
#pragma unroll
      for (int img = 0; img < 2; ++img) {
        float d00 = s_diff[img][li[0]][cj[0]], d01 = s_diff[img][li[0]][cj[1]], d02 = s_diff[img][li[0]][cj[2]];
        float d10 = s_diff[img][li[1]][cj[0]],                                   d12 = s_diff[img][li[1]][cj[2]];
        float d20 = s_diff[img][li[2]][cj[0]], d21 = s_diff[img][li[2]][cj[1]], d22 = s_diff[img][li[2]][cj[2]];
        float gx = 2.f * (d00 - d02) + 4.f * (d10 - d12) + 2.f * (d20 - d22);
        float gy = 2.f * d00 + 4.f * d01 + 2.f * d02 - 2.f * d20 - 4.f * d21 - 2.f * d22;
        ab[img] = fabsf(gx) + fabsf(gy);
      }
      val += fabsf(ab[0] - ab[1]);
    }
  }
  val *= scale;

  // block reduction: 256 threads = 4 waves
#pragma unroll
  for (int off = 32; off > 0; off >>= 1) val += __shfl_down(val, off, 64);
  __shared__ float wpart[4];
  if ((tid & 63) == 0) wpart[tid >> 6] = val;
  __syncthreads();
  if (tid == 0) atomicAdd(acc, (double)(wpart[0] + wpart[1] + wpart[2] + wpart[3]));
}

__global__ void finalize_kernel(const double* __restrict__ acc, float* __restrict__ out)
{
  out[0] = (float)acc[0];
}

extern "C" void kernel_launch(void* const* d_in, const int* in_sizes, int n_in,
                              void* d_out, int out_size, void* d_ws, size_t ws_size,
                              hipStream_t stream) {
  const float* in = (const float*)d_in[0];
  const float* tg = (const float*)d_in[1];
  float* out = (float*)d_out;

  double* acc = (double*)d_ws;
  float* base = (float*)((char*)d_ws + 16);
  const size_t s0 = (size_t)NCH * 256 * 256;
  const size_t s1 = (size_t)NCH * 128 * 128;
  float* d0i = base;
  float* d0t = d0i + s0;
  float* d1i = d0t + s0;
  float* d1t = d1i + s1;
  float* d2i = d1t + s1;
  float* d2t = d2i + (size_t)NCH * 64 * 64;

  hipMemsetAsync(d_ws, 0, 16, stream);

  const float* curs_i[3] = {in, d0i, d1i};
  const float* curs_t[3] = {tg, d0t, d1t};
  float* downs_i[3] = {d0i, d1i, d2i};
  float* downs_t[3] = {d0t, d1t, d2t};

  for (int lvl = 0; lvl < 3; ++lvl) {
    int H = 512 >> lvl, W = H, H2 = H >> 1, W2 = W >> 1;
    dim3 gdown((W2 + 63) / 64, H2, NCH);
    gauss_down_kernel<<<gdown, dim3(64), 0, stream>>>(curs_i[lvl], downs_i[lvl], H, W);
    gauss_down_kernel<<<gdown, dim3(64), 0, stream>>>(curs_t[lvl], downs_t[lvl], H, W);
    int HO = H + 2, WO = W + 2;
    dim3 gloss((WO + TW - 1) / TW, (HO + TH - 1) / TH, NCH);
    float scale = 1.f / ((float)NCH * HO * WO);
    lap_loss_tile_kernel<<<gloss, dim3(256), 0, stream>>>(
        curs_i[lvl], curs_t[lvl], downs_i[lvl], downs_t[lvl], H, W, scale, acc);
  }

  finalize_kernel<<<1, 1, 0, stream>>>(acc, out);
}

// Round 3
// 427.275 us; speedup vs baseline: 5.6193x; 1.1372x over previous
//
#include <hip/hip_runtime.h>

// Laplacian pyramid loss, 3 levels, B*C = 48 channels of 512x512 f32.
// Gaussian = outer([1,4,6,4,1])^2 / 256 (hardcoded, separable).

#define NCH 48
#define TW 32
#define TH 32

__device__ __forceinline__ int refl(int p, int n) {
  // jnp reflect pad (no edge repeat), |overshoot| <= 4 here, n >= 64
  return p < 0 ? -p : (p >= n ? 2 * n - 2 - p : p);
}

// ---------------- downsample: decimate(gauss5x5_reflect(cur)) ----------------
// Block: 256 threads -> 64 out-cols x 16 out-rows. Separable via LDS.
// s_in stores the (35 x 131) input tile DE-INTERLEAVED: even cols in slots
// [0,66), odd cols in [66,131)  -> phase-B reads are stride-1 (no conflicts).
#define GD_IR 35
#define GD_IC 131
#define GD_STR 132

__global__ __launch_bounds__(256) void gauss_down_kernel(
    const float* __restrict__ cur_in, const float* __restrict__ cur_tg,
    float* __restrict__ down_in, float* __restrict__ down_tg, int H, int W)
{
  const int H2 = H >> 1, W2 = W >> 1;
  const int z = blockIdx.z;
  const int img = (z >= NCH);
  const int n = z - (img ? NCH : 0);
  const float* cur = (img ? cur_tg : cur_in) + (size_t)n * H * W;
  float* down = (img ? down_tg : down_in) + (size_t)n * H2 * W2;
  const int w0 = blockIdx.x * 64;
  const int h0 = blockIdx.y * 16;
  const int tid = threadIdx.x;

  __shared__ float s_in[GD_IR][GD_STR];
  __shared__ float s_hs[GD_IR][64];

  // phase A: stage input with reflection, de-interleaved
  const int r0g = 2 * h0 - 2, c0g = 2 * w0 - 2;
  for (int idx = tid; idx < GD_IR * GD_IC; idx += 256) {
    int r = idx / GD_IC;               // const divisor -> magic mul
    int c = idx - r * GD_IC;
    int gr = refl(r0g + r, H);
    int gc = refl(c0g + c, W);
    int slot = (c & 1) ? (66 + (c >> 1)) : (c >> 1);
    s_in[r][slot] = cur[(size_t)gr * W + gc];
  }
  __syncthreads();

  // phase B: horizontal 5-tap {1,4,6,4,1} at even positions
  for (int idx = tid; idx < GD_IR * 64; idx += 256) {
    int r = idx >> 6;
    int wc = idx & 63;
    float e0 = s_in[r][wc], e1 = s_in[r][wc + 1], e2 = s_in[r][wc + 2];
    float o0 = s_in[r][66 + wc], o1 = s_in[r][66 + wc + 1];
    s_hs[r][wc] = e0 + e2 + 6.f * e1 + 4.f * (o0 + o1);
  }
  __syncthreads();

  // phase C: vertical 5-tap, 4 consecutive out-rows per thread, sliding by 2
  const int tx = tid & 63, ty = tid >> 6;
  const int rr = 8 * ty;
  float v0 = s_hs[rr][tx], v1 = s_hs[rr + 1][tx], v2 = s_hs[rr + 2][tx],
        v3 = s_hs[rr + 3][tx], v4 = s_hs[rr + 4][tx];
#pragma unroll
  for (int k = 0; k < 4; ++k) {
    int ho = h0 + 4 * ty + k;
    down[(size_t)ho * W2 + w0 + tx] =
        (v0 + v4 + 6.f * v2 + 4.f * (v1 + v3)) * (1.f / 256.f);
    if (k < 3) {
      v0 = v2; v1 = v3; v2 = v4;
      v3 = s_hs[rr + 2 * k + 5][tx];
      v4 = s_hs[rr + 2 * k + 6][tx];
    }
  }
}

// ---------------- fused: diff tile in LDS -> miniloss -> reduce ----------------
// up(down) separable per axis: weights [1,4,6,4,1]/8 on the zero-interleaved
// grid.  Unified parity trick: taps at full-grid positions f, f+2, f+4 with
// f = q-2+(q&1); weights even:{.125,.75,.125} odd:{.5,.5,0}. Reflection is on
// the FULL grid, then >>1 (half-grid reflect is NOT equivalent at the edge).
__global__ __launch_bounds__(256) void lap_loss_tile_kernel(
    const float* __restrict__ cur_in, const float* __restrict__ cur_tg,
    const float* __restrict__ down_in, const float* __restrict__ down_tg,
    int H, int W, float scale, double* __restrict__ acc)
{
  const int HO = H + 2, WO = W + 2;
  const int H2 = H >> 1, W2 = W >> 1;
  const int n = blockIdx.z;
  const int x0 = blockIdx.x * TW, y0 = blockIdx.y * TH;
  const int y_end = min(HO, y0 + TH), x_end = min(WO, x0 + TW);
  const int tid = threadIdx.x;

  // stored (reflected) diff row/col ranges
  int rlo = max(0, y0 - 2);
  if (y_end > H) rlo = min(rlo, 2 * H - 1 - y_end);
  const int rhi = min(H, y_end);
  int clo = max(0, x0 - 2);
  if (x_end > W) clo = min(clo, 2 * W - 1 - x_end);
  const int chi = min(W, x_end);
  const int u0 = (clo >= 2) ? ((clo - 2) >> 1) : 0;
  const int u1 = min(W2 - 1, (chi + 1) >> 1);

  __shared__ float s_tmp[2][TH + 2][20];
  __shared__ float s_diff[2][TH + 2][TW + 4];

  // ---- phase 1: vertical up-pass (global down -> s_tmp), branchless parity ----
  for (int img = 0; img < 2; ++img) {
    const float* dn = (img ? down_tg : down_in) + (size_t)n * H2 * W2;
    for (int idx = tid; idx < 34 * 20; idx += 256) {
      int l = idx / 20, du = idx - 20 * l;         // const divisor
      int p = min(rlo + l, H - 1);                 // clamp: rows >= nrows unused
      int u = min(u0 + du, u1);                    // clamp: cols >= NU unused
      int par = p & 1;
      int f = p - 2 + par;
      int t0 = refl(f, H) >> 1;
      int t1 = refl(f + 2, H) >> 1;
      int t2 = refl(f + 4, H) >> 1;
      float w0v = par ? 0.5f : 0.125f;
      float w1v = par ? 0.5f : 0.75f;
      float w2v = par ? 0.0f : 0.125f;
      s_tmp[img][l][du] = w0v * dn[(size_t)t0 * W2 + u]
                        + w1v * dn[(size_t)t1 * W2 + u]
                        + w2v * dn[(size_t)t2 * W2 + u];
    }
  }
  __syncthreads();

  // ---- phase 2: horizontal up-pass + cur load -> diff in LDS ----
  for (int img = 0; img < 2; ++img) {
    const float* cp = (img ? cur_tg : cur_in) + (size_t)n * H * W;
    for (int idx = tid; idx < 34 * 36; idx += 256) {
      int l = idx / 36, c = idx - 36 * l;          // const divisor
      int p = min(rlo + l, H - 1);
      int q = min(clo + c, W - 1);
      int par = q & 1;
      int f = q - 2 + par;
      int tA = (refl(f, W) >> 1) - u0;
      int tB = (refl(f + 2, W) >> 1) - u0;
      int tC = (refl(f + 4, W) >> 1) - u0;
      float w0v = par ? 0.5f : 0.125f;
      float w1v = par ? 0.5f : 0.75f;
      float w2v = par ? 0.0f : 0.125f;
      float up = w0v * s_tmp[img][l][tA] + w1v * s_tmp[img][l][tB]
               + w2v * s_tmp[img][l][tC];
      s_diff[img][l][c] = cp[(size_t)p * W + q] - up;
    }
  }
  __syncthreads();

  // ---- phase 3: 3x3 |gx|+|gy|, sliding window down 4 consecutive rows ----
  float val = 0.f;
  const int tx = tid & 31;
  const int tg8 = tid >> 5;
  const int xx = x0 + tx;
  if (xx < x_end) {
    const int cj0 = refl(xx - 2, W) - clo;
    const int cj1 = refl(xx - 1, W) - clo;
    const int cj2 = refl(xx, W) - clo;
    int yy = y0 + 4 * tg8;
    const int rA = refl(yy - 2, H) - rlo;
    const int rB = refl(yy - 1, H) - rlo;
    float A0[2], A1[2], B0[2], B1[2];
#pragma unroll
    for (int img = 0; img < 2; ++img) {
      float d0 = s_diff[img][rA][cj0], d1 = s_diff[img][rA][cj1], d2 = s_diff[img][rA][cj2];
      A0[img] = d0 - d2;
      B0[img] = 2.f * d0 + 4.f * d1 + 2.f * d2;
      d0 = s_diff[img][rB][cj0]; d1 = s_diff[img][rB][cj1]; d2 = s_diff[img][rB][cj2];
      A1[img] = d0 - d2;
      B1[img] = 2.f * d0 + 4.f * d1 + 2.f * d2;
    }
#pragma unroll
    for (int k = 0; k < 4; ++k, ++yy) {
      if (yy >= y_end) break;
      const int rC = refl(yy, H) - rlo;
      float ab[2];
#pragma unroll
      for (int img = 0; img < 2; ++img) {
        float d0 = s_diff[img][rC][cj0], d1 = s_diff[img][rC][cj1], d2 = s_diff[img][rC][cj2];
        float A2 = d0 - d2;
        float B2 = 2.f * d0 + 4.f * d1 + 2.f * d2;
        float gx = 2.f * A0[img] + 4.f * A1[img] + 2.f * A2;
        float gy = B0[img] - B2;
        ab[img] = fabsf(gx) + fabsf(gy);
        A0[img] = A1[img]; A1[img] = A2;
        B0[img] = B1[img]; B1[img] = B2;
      }
      val += fabsf(ab[0] - ab[1]);
    }
  }
  val *= scale;

  // block reduction: 256 threads = 4 waves
#pragma unroll
  for (int off = 32; off > 0; off >>= 1) val += __shfl_down(val, off, 64);
  __shared__ float wpart[4];
  if ((tid & 63) == 0) wpart[tid >> 6] = val;
  __syncthreads();
  if (tid == 0) atomicAdd(acc, (double)(wpart[0] + wpart[1] + wpart[2] + wpart[3]));
}

__global__ void finalize_kernel(const double* __restrict__ acc, float* __restrict__ out)
{
  out[0] = (float)acc[0];
}

extern "C" void kernel_launch(void* const* d_in, const int* in_sizes, int n_in,
                              void* d_out, int out_size, void* d_ws, size_t ws_size,
                              hipStream_t stream) {
  const float* in = (const float*)d_in[0];
  const float* tg = (const float*)d_in[1];
  float* out = (float*)d_out;

  double* acc = (double*)d_ws;
  float* base = (float*)((char*)d_ws + 16);
  const size_t s0 = (size_t)NCH * 256 * 256;
  const size_t s1 = (size_t)NCH * 128 * 128;
  float* d0i = base;
  float* d0t = d0i + s0;
  float* d1i = d0t + s0;
  float* d1t = d1i + s1;
  float* d2i = d1t + s1;
  float* d2t = d2i + (size_t)NCH * 64 * 64;

  hipMemsetAsync(d_ws, 0, 16, stream);

  const float* curs_i[3] = {in, d0i, d1i};
  const float* curs_t[3] = {tg, d0t, d1t};
  float* downs_i[3] = {d0i, d1i, d2i};
  float* downs_t[3] = {d0t, d1t, d2t};

  for (int lvl = 0; lvl < 3; ++lvl) {
    int H = 512 >> lvl, W = H, H2 = H >> 1, W2 = W >> 1;
    dim3 gdown(W2 / 64, H2 / 16, 2 * NCH);
    gauss_down_kernel<<<gdown, dim3(256), 0, stream>>>(
        curs_i[lvl], curs_t[lvl], downs_i[lvl], downs_t[lvl], H, W);
    int HO = H + 2, WO = W + 2;
    dim3 gloss((WO + TW - 1) / TW, (HO + TH - 1) / TH, NCH);
    float scale = 1.f / ((float)NCH * HO * WO);
    lap_loss_tile_kernel<<<gloss, dim3(256), 0, stream>>>(
        curs_i[lvl], curs_t[lvl], downs_i[lvl], downs_t[lvl], H, W, scale, acc);
  }

  finalize_kernel<<<1, 1, 0, stream>>>(acc, out);
}

// Round 4
// 419.132 us; speedup vs baseline: 5.7285x; 1.0194x over previous
//
#include <hip/hip_runtime.h>

// Laplacian pyramid loss, 3 levels, B*C = 48 channels of 512x512 f32.
// Gaussian = outer([1,4,6,4,1])^2 / 256 (hardcoded, separable).

#define NCH 48
#define TW 32
#define TH 32

__device__ __forceinline__ int refl(int p, int n) {
  // jnp reflect pad (no edge repeat), |overshoot| <= 4 here, n >= 64
  return p < 0 ? -p : (p >= n ? 2 * n - 2 - p : p);
}

// ---------------- downsample: decimate(gauss5x5_reflect(cur)) ----------------
#define GD_IR 35
#define GD_IC 131
#define GD_STR 132

__global__ __launch_bounds__(256) void gauss_down_kernel(
    const float* __restrict__ cur_in, const float* __restrict__ cur_tg,
    float* __restrict__ down_in, float* __restrict__ down_tg, int H, int W)
{
  const int H2 = H >> 1, W2 = W >> 1;
  const int z = blockIdx.z;
  const int img = (z >= NCH);
  const int n = z - (img ? NCH : 0);
  const float* cur = (img ? cur_tg : cur_in) + (size_t)n * H * W;
  float* down = (img ? down_tg : down_in) + (size_t)n * H2 * W2;
  const int w0 = blockIdx.x * 64;
  const int h0 = blockIdx.y * 16;
  const int tid = threadIdx.x;

  __shared__ float s_in[GD_IR][GD_STR];
  __shared__ float s_hs[GD_IR][64];

  const int r0g = 2 * h0 - 2, c0g = 2 * w0 - 2;
  for (int idx = tid; idx < GD_IR * GD_IC; idx += 256) {
    int r = idx / GD_IC;
    int c = idx - r * GD_IC;
    int gr = refl(r0g + r, H);
    int gc = refl(c0g + c, W);
    int slot = (c & 1) ? (66 + (c >> 1)) : (c >> 1);
    s_in[r][slot] = cur[(size_t)gr * W + gc];
  }
  __syncthreads();

  for (int idx = tid; idx < GD_IR * 64; idx += 256) {
    int r = idx >> 6;
    int wc = idx & 63;
    float e0 = s_in[r][wc], e1 = s_in[r][wc + 1], e2 = s_in[r][wc + 2];
    float o0 = s_in[r][66 + wc], o1 = s_in[r][66 + wc + 1];
    s_hs[r][wc] = e0 + e2 + 6.f * e1 + 4.f * (o0 + o1);
  }
  __syncthreads();

  const int tx = tid & 63, ty = tid >> 6;
  const int rr = 8 * ty;
  float v0 = s_hs[rr][tx], v1 = s_hs[rr + 1][tx], v2 = s_hs[rr + 2][tx],
        v3 = s_hs[rr + 3][tx], v4 = s_hs[rr + 4][tx];
#pragma unroll
  for (int k = 0; k < 4; ++k) {
    int ho = h0 + 4 * ty + k;
    down[(size_t)ho * W2 + w0 + tx] =
        (v0 + v4 + 6.f * v2 + 4.f * (v1 + v3)) * (1.f / 256.f);
    if (k < 3) {
      v0 = v2; v1 = v3; v2 = v4;
      v3 = s_hs[rr + 2 * k + 5][tx];
      v4 = s_hs[rr + 2 * k + 6][tx];
    }
  }
}

// ---------------- fused diff + miniloss + reduce ----------------
// up(down): separable [1,4,6,4,1]/8 per axis on the zero-interleaved grid:
// even coord -> {.125,.75,.125} on down taps u-1,u,u+1; odd -> {.5,.5} on u,u+1.
// Fast path (block-uniform) for tiles where no reflection can occur.
__global__ __launch_bounds__(256) void lap_loss_tile_kernel(
    const float* __restrict__ cur_in, const float* __restrict__ cur_tg,
    const float* __restrict__ down_in, const float* __restrict__ down_tg,
    int H, int W, float scale, double* __restrict__ acc)
{
  const int HO = H + 2, WO = W + 2;
  const int H2 = H >> 1, W2 = W >> 1;
  const int n = blockIdx.z;
  const int x0 = blockIdx.x * TW, y0 = blockIdx.y * TH;
  const int tid = threadIdx.x;

  __shared__ __align__(16) float s_down[2][19][28];
  __shared__ __align__(16) float s_tmp[2][34][28];
  __shared__ __align__(16) float s_diff[2][34][36];

  float val = 0.f;

  const bool fast = (x0 >= 8) && (x0 + 40 <= W) && (y0 >= 8) && (y0 + 40 <= H);

  if (fast) {
    const int dr0 = (y0 >> 1) - 2;   // first staged down row
    const int du0 = (x0 >> 1) - 4;   // first staged down col (16B aligned)

    // ---- phase A: stage down tile, one float4 per thread ----
    if (tid < 228) {
      int img = tid / 114, j = tid % 114;
      int r = j / 6, c4 = j - 6 * r;
      const float* dn = (img ? down_tg : down_in) + (size_t)n * H2 * W2;
      float4 v = reinterpret_cast<const float4*>(dn)[(((size_t)(dr0 + r)) * W2 + du0 + 4 * c4) >> 2];
      *reinterpret_cast<float4*>(&s_down[img][r][4 * c4]) = v;
    }
    __syncthreads();

    // ---- phase B: vertical up-pass, float4, even/odd split ----
    for (int t = tid; t < 408; t += 256) {
      int img = t / 204, j = t - 204 * img;
      int lh = j / 102, k = j - 102 * lh;      // lh: 0=even rows, 1=odd rows
      int li = k / 6, c4 = k - 6 * li;
      int l = 2 * li + lh;
      int r0 = (l + lh) >> 1;
      float4 a = *reinterpret_cast<const float4*>(&s_down[img][r0][4 * c4]);
      float4 b = *reinterpret_cast<const float4*>(&s_down[img][r0 + 1][4 * c4]);
      float4 o;
      if (lh == 0) {
        float4 c = *reinterpret_cast<const float4*>(&s_down[img][r0 + 2][4 * c4]);
        o.x = 0.125f * (a.x + c.x) + 0.75f * b.x;
        o.y = 0.125f * (a.y + c.y) + 0.75f * b.y;
        o.z = 0.125f * (a.z + c.z) + 0.75f * b.z;
        o.w = 0.125f * (a.w + c.w) + 0.75f * b.w;
      } else {
        o.x = 0.5f * (a.x + b.x);
        o.y = 0.5f * (a.y + b.y);
        o.z = 0.5f * (a.z + b.z);
        o.w = 0.5f * (a.w + b.w);
      }
      *reinterpret_cast<float4*>(&s_tmp[img][l][4 * c4]) = o;
    }
    __syncthreads();

    // ---- phase C: horizontal up + cur (float4) -> diff ----
    for (int t = tid; t < 612; t += 256) {
      int img = t / 306, j = t - 306 * img;
      int l = j / 9, c4 = j - 9 * l;
      int q0 = x0 - 4 + 4 * c4;                // even, 16B aligned
      int uc = 2 * c4 + 2;                     // (q0>>1) - du0
      const float* st = s_tmp[img][l];
      float Tm1 = st[uc - 1], T0 = st[uc], T1 = st[uc + 1], T2 = st[uc + 2];
      const float* cp = (img ? cur_tg : cur_in) + (size_t)n * H * W;
      float4 c = reinterpret_cast<const float4*>(cp)[((size_t)(y0 - 2 + l) * W + q0) >> 2];
      float4 d;
      d.x = c.x - (0.125f * (Tm1 + T1) + 0.75f * T0);
      d.y = c.y - 0.5f * (T0 + T1);
      d.z = c.z - (0.125f * (T0 + T2) + 0.75f * T1);
      d.w = c.w - 0.5f * (T1 + T2);
      *reinterpret_cast<float4*>(&s_diff[img][l][4 * c4]) = d;
    }
    __syncthreads();

    // ---- phase D: Sobel miniloss, 4 outputs per thread ----
    {
      const int tx = tid & 7, ty = tid >> 3;   // x = x0+4*tx .. +3, y = y0+ty
      float ab[2][4];
#pragma unroll
      for (int img = 0; img < 2; ++img) {
        float a[3][6];
#pragma unroll
        for (int r = 0; r < 3; ++r) {
          const float* row = s_diff[img][ty + r];
          float4 M = *reinterpret_cast<const float4*>(&row[4 * tx]);
          float4 R = *reinterpret_cast<const float4*>(&row[4 * tx + 4]);
          a[r][0] = M.z; a[r][1] = M.w; a[r][2] = R.x;
          a[r][3] = R.y; a[r][4] = R.z; a[r][5] = R.w;
        }
#pragma unroll
        for (int jj = 0; jj < 4; ++jj) {
          float tA = a[0][jj] - a[0][jj + 2];
          float tB = a[1][jj] - a[1][jj + 2];
          float tC = a[2][jj] - a[2][jj + 2];
          float gx = 2.f * (tA + tC) + 4.f * tB;
          float SA = 2.f * (a[0][jj] + a[0][jj + 2]) + 4.f * a[0][jj + 1];
          float SC = 2.f * (a[2][jj] + a[2][jj + 2]) + 4.f * a[2][jj + 1];
          ab[img][jj] = fabsf(gx) + fabsf(SA - SC);
        }
      }
#pragma unroll
      for (int jj = 0; jj < 4; ++jj) val += fabsf(ab[0][jj] - ab[1][jj]);
      val *= scale;
    }
  } else {
    // ---------------- generic (edge) path: R3 logic ----------------
    const int y_end = min(HO, y0 + TH), x_end = min(WO, x0 + TW);
    int rlo = max(0, y0 - 2);
    if (y_end > H) rlo = min(rlo, 2 * H - 1 - y_end);
    int clo = max(0, x0 - 2);
    if (x_end > W) clo = min(clo, 2 * W - 1 - x_end);
    const int chi = min(W, x_end);
    const int u0 = (clo >= 2) ? ((clo - 2) >> 1) : 0;
    const int u1 = min(W2 - 1, (chi + 1) >> 1);

    for (int img = 0; img < 2; ++img) {
      const float* dn = (img ? down_tg : down_in) + (size_t)n * H2 * W2;
      for (int idx = tid; idx < 34 * 20; idx += 256) {
        int l = idx / 20, du = idx - 20 * l;
        int p = min(rlo + l, H - 1);
        int u = min(u0 + du, u1);
        int par = p & 1;
        int f = p - 2 + par;
        int t0 = refl(f, H) >> 1;
        int t1 = refl(f + 2, H) >> 1;
        int t2 = refl(f + 4, H) >> 1;
        float w0v = par ? 0.5f : 0.125f;
        float w1v = par ? 0.5f : 0.75f;
        float w2v = par ? 0.0f : 0.125f;
        s_tmp[img][l][du] = w0v * dn[(size_t)t0 * W2 + u]
                          + w1v * dn[(size_t)t1 * W2 + u]
                          + w2v * dn[(size_t)t2 * W2 + u];
      }
    }
    __syncthreads();

    for (int img = 0; img < 2; ++img) {
      const float* cp = (img ? cur_tg : cur_in) + (size_t)n * H * W;
      for (int idx = tid; idx < 34 * 36; idx += 256) {
        int l = idx / 36, c = idx - 36 * l;
        int p = min(rlo + l, H - 1);
        int q = min(clo + c, W - 1);
        int par = q & 1;
        int f = q - 2 + par;
        int tA = (refl(f, W) >> 1) - u0;
        int tB = (refl(f + 2, W) >> 1) - u0;
        int tC = (refl(f + 4, W) >> 1) - u0;
        float w0v = par ? 0.5f : 0.125f;
        float w1v = par ? 0.5f : 0.75f;
        float w2v = par ? 0.0f : 0.125f;
        float up = w0v * s_tmp[img][l][tA] + w1v * s_tmp[img][l][tB]
                 + w2v * s_tmp[img][l][tC];
        s_diff[img][l][c] = cp[(size_t)p * W + q] - up;
      }
    }
    __syncthreads();

    const int tx = tid & 31;
    const int tg8 = tid >> 5;
    const int xx = x0 + tx;
    if (xx < x_end) {
      const int cj0 = refl(xx - 2, W) - clo;
      const int cj1 = refl(xx - 1, W) - clo;
      const int cj2 = refl(xx, W) - clo;
      int yy = y0 + 4 * tg8;
      const int rA = refl(yy - 2, H) - rlo;
      const int rB = refl(yy - 1, H) - rlo;
      float A0[2], A1[2], B0[2], B1[2];
#pragma unroll
      for (int img = 0; img < 2; ++img) {
        float d0 = s_diff[img][rA][cj0], d1 = s_diff[img][rA][cj1], d2 = s_diff[img][rA][cj2];
        A0[img] = d0 - d2;
        B0[img] = 2.f * d0 + 4.f * d1 + 2.f * d2;
        d0 = s_diff[img][rB][cj0]; d1 = s_diff[img][rB][cj1]; d2 = s_diff[img][rB][cj2];
        A1[img] = d0 - d2;
        B1[img] = 2.f * d0 + 4.f * d1 + 2.f * d2;
      }
#pragma unroll
      for (int k = 0; k < 4; ++k, ++yy) {
        if (yy >= y_end) break;
        const int rC = refl(yy, H) - rlo;
        float ab2[2];
#pragma unroll
        for (int img = 0; img < 2; ++img) {
          float d0 = s_diff[img][rC][cj0], d1 = s_diff[img][rC][cj1], d2 = s_diff[img][rC][cj2];
          float A2 = d0 - d2;
          float B2 = 2.f * d0 + 4.f * d1 + 2.f * d2;
          float gx = 2.f * A0[img] + 4.f * A1[img] + 2.f * A2;
          float gy = B0[img] - B2;
          ab2[img] = fabsf(gx) + fabsf(gy);
          A0[img] = A1[img]; A1[img] = A2;
          B0[img] = B1[img]; B1[img] = B2;
        }
        val += fabsf(ab2[0] - ab2[1]);
      }
    }
    val *= scale;
  }

  // ---- block reduction: 256 threads = 4 waves ----
#pragma unroll
  for (int off = 32; off > 0; off >>= 1) val += __shfl_down(val, off, 64);
  __shared__ float wpart[4];
  if ((tid & 63) == 0) wpart[tid >> 6] = val;
  __syncthreads();
  if (tid == 0) atomicAdd(acc, (double)(wpart[0] + wpart[1] + wpart[2] + wpart[3]));
}

__global__ void finalize_kernel(const double* __restrict__ acc, float* __restrict__ out)
{
  out[0] = (float)acc[0];
}

extern "C" void kernel_launch(void* const* d_in, const int* in_sizes, int n_in,
                              void* d_out, int out_size, void* d_ws, size_t ws_size,
                              hipStream_t stream) {
  const float* in = (const float*)d_in[0];
  const float* tg = (const float*)d_in[1];
  float* out = (float*)d_out;

  double* acc = (double*)d_ws;
  float* base = (float*)((char*)d_ws + 16);
  const size_t s0 = (size_t)NCH * 256 * 256;
  const size_t s1 = (size_t)NCH * 128 * 128;
  float* d0i = base;
  float* d0t = d0i + s0;
  float* d1i = d0t + s0;
  float* d1t = d1i + s1;
  float* d2i = d1t + s1;
  float* d2t = d2i + (size_t)NCH * 64 * 64;

  hipMemsetAsync(d_ws, 0, 16, stream);

  const float* curs_i[3] = {in, d0i, d1i};
  const float* curs_t[3] = {tg, d0t, d1t};
  float* downs_i[3] = {d0i, d1i, d2i};
  float* downs_t[3] = {d0t, d1t, d2t};

  for (int lvl = 0; lvl < 3; ++lvl) {
    int H = 512 >> lvl, W = H, H2 = H >> 1, W2 = W >> 1;
    dim3 gdown(W2 / 64, H2 / 16, 2 * NCH);
    gauss_down_kernel<<<gdown, dim3(256), 0, stream>>>(
        curs_i[lvl], curs_t[lvl], downs_i[lvl], downs_t[lvl], H, W);
    int HO = H + 2, WO = W + 2;
    dim3 gloss((WO + TW - 1) / TW, (HO + TH - 1) / TH, NCH);
    float scale = 1.f / ((float)NCH * HO * WO);
    lap_loss_tile_kernel<<<gloss, dim3(256), 0, stream>>>(
        curs_i[lvl], curs_t[lvl], downs_i[lvl], downs_t[lvl], H, W, scale, acc);
  }

  finalize_kernel<<<1, 1, 0, stream>>>(acc, out);
}

// Round 5
// 388.866 us; speedup vs baseline: 6.1744x; 1.0778x over previous
//
#include <hip/hip_runtime.h>

// Laplacian pyramid loss, 3 levels, B*C = 48 channels of 512x512 f32.
// FULLY FUSED: each level is ONE kernel that (a) stages cur tile in LDS,
// (b) computes the 5x5-separable gauss-down tile in LDS, (c) writes its owned
// disjoint 16x16 chunk of down to global (input of next level), (d) upsamples
// (separable, parity-split), (e) diff in-place over staged cur, (f) 3x3 Sobel
// miniloss |in-tg|, (g) block-reduce + atomic.  Gaussian = outer([1,4,6,4,1])^2/256.

#define NCH 48

__device__ __forceinline__ int refl(int p, int n) {
  // jnp reflect (no edge repeat); valid for p >= -(n-1), p <= 2n-2
  return p < 0 ? -p : (p >= n ? 2 * n - 2 - p : p);
}

__global__ __launch_bounds__(256) void lap_fused_kernel(
    const float* __restrict__ cur_in, const float* __restrict__ cur_tg,
    float* __restrict__ down_in, float* __restrict__ down_tg,
    int H, int W, float scale, int write_down, double* __restrict__ acc)
{
  const int HO = H + 2;
  const int H2 = H >> 1, W2 = W >> 1;
  const int n = blockIdx.z;
  const int bx = blockIdx.x, by = blockIdx.y;
  const int x0 = bx * 32, y0 = by * 32;
  const int tid = threadIdx.x;

  // s_cur: staged cur rows [r0, r0+40], cols [c0, c0+67]; later holds diff in-place.
  __shared__ __align__(16) float s_cur[2][41][68];
  __shared__ __align__(16) float s_hb[2][41][28];   // horizontal gauss; aliased as s_tmp
  __shared__ __align__(16) float s_down[2][19][28];
  float (*s_tmp)[34][28] = reinterpret_cast<float (*)[34][28]>(&s_hb[0][0][0]);

  const float* curp[2] = {cur_in + (size_t)n * H * W, cur_tg + (size_t)n * H * W};
  float* dwp[2] = {down_in + (size_t)n * H2 * W2, down_tg + (size_t)n * H2 * W2};

  const bool fast = (x0 >= 12) && (x0 + 55 < W) && (y0 >= 6) && (y0 + 34 < H);

  // tile geometry (R3-proven reflected ranges)
  const int y_end = min(HO, y0 + 32), x_end = min(HO, x0 + 32);
  int rlo = max(0, y0 - 2);
  if (y_end > H) rlo = min(rlo, 2 * H - 1 - y_end);
  int clo = max(0, x0 - 2);
  if (x_end > W) clo = min(clo, 2 * W - 1 - x_end);
  const int nrows = min(H, y_end) - rlo;
  const int ncols = min(W, x_end) - clo;

  const int dr0 = fast ? (y0 >> 1) - 2 : (max(0, rlo - 2) >> 1);
  const int du0 = fast ? (x0 >> 1) - 4 : (max(0, clo - 2) >> 1);
  const int r0 = 2 * dr0 - 2;     // staged cur row 0 (abs)
  const int c0 = 2 * du0 - 4;     // staged cur col 0 (abs); fast: x0-12, 16B aligned

  // ---- phase A: stage cur (41 x 68) x 2 images ----
  if (fast) {
    for (int t = tid; t < 2 * 41 * 17; t += 256) {
      int img = t / 697, j = t - 697 * img;
      int r = j / 17, c4 = j - 17 * r;
      const float4* src = reinterpret_cast<const float4*>(curp[img]);
      float4 v = src[(((size_t)(r0 + r) * W + c0) >> 2) + c4];
      *reinterpret_cast<float4*>(&s_cur[img][r][4 * c4]) = v;
    }
  } else {
    for (int t = tid; t < 2 * 41 * 68; t += 256) {
      int img = t / 2788, j = t - 2788 * img;
      int r = j / 68, c = j - 68 * r;
      s_cur[img][r][c] = curp[img][(size_t)refl(r0 + r, H) * W + refl(c0 + c, W)];
    }
  }
  __syncthreads();

  // ---- phase B: horizontal gauss {1,4,6,4,1} at even cols (down col du0+d) ----
  for (int t = tid; t < 2 * 41 * 28; t += 256) {
    int img = t / 1148, j = t - 1148 * img;
    int r = j / 28, d = j - 28 * r;
    const float* row = s_cur[img][r];
    s_hb[img][r][d] = row[2 * d + 2] + row[2 * d + 6] + 6.f * row[2 * d + 4]
                    + 4.f * (row[2 * d + 3] + row[2 * d + 5]);
  }
  __syncthreads();

  // ---- phase C: vertical gauss -> s_down (rows dr0+k) ----
  for (int t = tid; t < 2 * 19 * 28; t += 256) {
    int img = t / 532, j = t - 532 * img;
    int k = j / 28, d = j - 28 * k;
    s_down[img][k][d] = (s_hb[img][2 * k][d] + s_hb[img][2 * k + 4][d]
                       + 6.f * s_hb[img][2 * k + 2][d]
                       + 4.f * (s_hb[img][2 * k + 1][d] + s_hb[img][2 * k + 3][d]))
                      * (1.f / 256.f);
  }
  __syncthreads();

  // ---- phase W: write owned (disjoint) 16x16 chunk of down ----
  if (write_down) {
    for (int t = tid; t < 512; t += 256) {
      int img = t >> 8, k = (t & 255) >> 4, c = t & 15;
      int row = 16 * by + k, col = 16 * bx + c;
      if (row < H2 && col < W2)
        dwp[img][(size_t)row * W2 + col] = s_down[img][row - dr0][col - du0];
    }
  }

  // ---- phase D: vertical up-pass -> s_tmp (rows rlo+l) ----
  if (fast) {
    for (int t = tid; t < 476; t += 256) {
      int img = t / 238, j = t - 238 * img;
      int lh = j / 119, k2 = j - 119 * lh;
      int li = k2 / 7, c4 = k2 - 7 * li;
      int l = 2 * li + lh;
      int rr = (l + lh) >> 1;
      float4 a = *reinterpret_cast<const float4*>(&s_down[img][rr][4 * c4]);
      float4 b = *reinterpret_cast<const float4*>(&s_down[img][rr + 1][4 * c4]);
      float4 o;
      if (lh == 0) {
        float4 cc = *reinterpret_cast<const float4*>(&s_down[img][rr + 2][4 * c4]);
        o.x = 0.125f * (a.x + cc.x) + 0.75f * b.x;
        o.y = 0.125f * (a.y + cc.y) + 0.75f * b.y;
        o.z = 0.125f * (a.z + cc.z) + 0.75f * b.z;
        o.w = 0.125f * (a.w + cc.w) + 0.75f * b.w;
      } else {
        o.x = 0.5f * (a.x + b.x);
        o.y = 0.5f * (a.y + b.y);
        o.z = 0.5f * (a.z + b.z);
        o.w = 0.5f * (a.w + b.w);
      }
      *reinterpret_cast<float4*>(&s_tmp[img][l][4 * c4]) = o;
    }
  } else {
    for (int t = tid; t < 2 * 34 * 28; t += 256) {
      int img = t / 952, j = t - 952 * img;
      int l = j / 28, du = j - 28 * l;
      int p = min(rlo + l, H - 1);
      int ur = min(du, W2 - 1 - du0);
      int par = p & 1;
      int f = p - 2 + par;
      int t0 = (refl(f, H) >> 1) - dr0;
      int t1 = (refl(f + 2, H) >> 1) - dr0;
      int t2 = (refl(f + 4, H) >> 1) - dr0;
      float w0v = par ? 0.5f : 0.125f;
      float w1v = par ? 0.5f : 0.75f;
      float w2v = par ? 0.0f : 0.125f;
      s_tmp[img][l][du] = w0v * s_down[img][t0][ur] + w1v * s_down[img][t1][ur]
                        + w2v * s_down[img][t2][ur];
    }
  }
  __syncthreads();

  // ---- phase E: horizontal up + diff, in place over s_cur ----
  if (fast) {
    for (int t = tid; t < 612; t += 256) {
      int img = t / 306, j = t - 306 * img;
      int l = j / 9, c4 = j - 9 * l;
      float4 c = *reinterpret_cast<const float4*>(&s_cur[img][l + 4][8 + 4 * c4]);
      const float* st = s_tmp[img][l];
      int uc = 2 * c4 + 2;
      float Tm1 = st[uc - 1], T0 = st[uc], T1 = st[uc + 1], T2 = st[uc + 2];
      float4 d;
      d.x = c.x - (0.125f * (Tm1 + T1) + 0.75f * T0);
      d.y = c.y - 0.5f * (T0 + T1);
      d.z = c.z - (0.125f * (T0 + T2) + 0.75f * T1);
      d.w = c.w - 0.5f * (T1 + T2);
      *reinterpret_cast<float4*>(&s_cur[img][l + 4][8 + 4 * c4]) = d;
    }
  } else {
    for (int t = tid; t < 2 * 34 * 36; t += 256) {
      int img = t / 1224, j = t - 1224 * img;
      int l = j / 36, cc = j - 36 * l;
      if (l < nrows && cc < ncols) {
        int p = rlo + l, q = clo + cc;
        int par = q & 1;
        int f = q - 2 + par;
        int tA = (refl(f, W) >> 1) - du0;
        int tB = (refl(f + 2, W) >> 1) - du0;
        int tC = (refl(f + 4, W) >> 1) - du0;
        float w0v = par ? 0.5f : 0.125f;
        float w1v = par ? 0.5f : 0.75f;
        float w2v = par ? 0.0f : 0.125f;
        float up = w0v * s_tmp[img][l][tA] + w1v * s_tmp[img][l][tB]
                 + w2v * s_tmp[img][l][tC];
        s_cur[img][p - r0][q - c0] -= up;
      }
    }
  }
  __syncthreads();

  // ---- phase F: 3x3 |gx|+|gy| miniloss, |in - tg| ----
  float val = 0.f;
  if (fast) {
    const int tx = tid & 7, ty = tid >> 3;   // x = x0+4*tx..+3, y = y0+ty
    float ab[2][4];
#pragma unroll
    for (int img = 0; img < 2; ++img) {
      float a[3][6];
#pragma unroll
      for (int r = 0; r < 3; ++r) {
        const float* row = s_cur[img][ty + r + 4];
        float4 M = *reinterpret_cast<const float4*>(&row[4 * tx + 8]);
        float4 R = *reinterpret_cast<const float4*>(&row[4 * tx + 12]);
        a[r][0] = M.z; a[r][1] = M.w; a[r][2] = R.x;
        a[r][3] = R.y; a[r][4] = R.z; a[r][5] = R.w;
      }
#pragma unroll
      for (int jj = 0; jj < 4; ++jj) {
        float tA = a[0][jj] - a[0][jj + 2];
        float tB = a[1][jj] - a[1][jj + 2];
        float tC = a[2][jj] - a[2][jj + 2];
        float gx = 2.f * (tA + tC) + 4.f * tB;
        float SA = 2.f * (a[0][jj] + a[0][jj + 2]) + 4.f * a[0][jj + 1];
        float SC = 2.f * (a[2][jj] + a[2][jj + 2]) + 4.f * a[2][jj + 1];
        ab[img][jj] = fabsf(gx) + fabsf(SA - SC);
      }
    }
#pragma unroll
    for (int jj = 0; jj < 4; ++jj) val += fabsf(ab[0][jj] - ab[1][jj]);
  } else {
    const int tx = tid & 31, tg8 = tid >> 5;
    const int xx = x0 + tx;
    if (xx < x_end) {
      const int cj0 = refl(xx - 2, W) - c0;
      const int cj1 = refl(xx - 1, W) - c0;
      const int cj2 = refl(xx, W) - c0;
      for (int k = 0; k < 4; ++k) {
        int yy = y0 + 4 * tg8 + k;
        if (yy >= y_end) break;
        int ri0 = refl(yy - 2, H) - r0;
        int ri1 = refl(yy - 1, H) - r0;
        int ri2 = refl(yy, H) - r0;
        float ab2[2];
#pragma unroll
        for (int img = 0; img < 2; ++img) {
          float d00 = s_cur[img][ri0][cj0], d01 = s_cur[img][ri0][cj1], d02 = s_cur[img][ri0][cj2];
          float d10 = s_cur[img][ri1][cj0],                              d12 = s_cur[img][ri1][cj2];
          float d20 = s_cur[img][ri2][cj0], d21 = s_cur[img][ri2][cj1], d22 = s_cur[img][ri2][cj2];
          float gx = 2.f * (d00 - d02) + 4.f * (d10 - d12) + 2.f * (d20 - d22);
          float gy = 2.f * d00 + 4.f * d01 + 2.f * d02 - 2.f * d20 - 4.f * d21 - 2.f * d22;
          ab2[img] = fabsf(gx) + fabsf(gy);
        }
        val += fabsf(ab2[0] - ab2[1]);
      }
    }
  }
  val *= scale;

  // ---- reduction: 256 threads = 4 waves ----
#pragma unroll
  for (int off = 32; off > 0; off >>= 1) val += __shfl_down(val, off, 64);
  __shared__ float wpart[4];
  if ((tid & 63) == 0) wpart[tid >> 6] = val;
  __syncthreads();
  if (tid == 0) atomicAdd(acc, (double)(wpart[0] + wpart[1] + wpart[2] + wpart[3]));
}

__global__ void finalize_kernel(const double* __restrict__ acc, float* __restrict__ out)
{
  out[0] = (float)acc[0];
}

extern "C" void kernel_launch(void* const* d_in, const int* in_sizes, int n_in,
                              void* d_out, int out_size, void* d_ws, size_t ws_size,
                              hipStream_t stream) {
  const float* in = (const float*)d_in[0];
  const float* tg = (const float*)d_in[1];
  float* out = (float*)d_out;

  double* acc = (double*)d_ws;
  float* base = (float*)((char*)d_ws + 16);
  const size_t s0 = (size_t)NCH * 256 * 256;
  const size_t s1 = (size_t)NCH * 128 * 128;
  float* d0i = base;
  float* d0t = d0i + s0;
  float* d1i = d0t + s0;
  float* d1t = d1i + s1;

  hipMemsetAsync(d_ws, 0, 16, stream);

  const float* ci[3] = {in, d0i, d1i};
  const float* ct[3] = {tg, d0t, d1t};
  float* di[3] = {d0i, d1i, d1i};   // level 2 down unused (write_down=0)
  float* dt[3] = {d0t, d1t, d1t};

  for (int lvl = 0; lvl < 3; ++lvl) {
    int H = 512 >> lvl;
    int HO = H + 2;
    int T = (HO + 31) / 32;
    dim3 grid(T, T, NCH);
    float scale = 1.f / ((float)NCH * HO * HO);
    lap_fused_kernel<<<grid, dim3(256), 0, stream>>>(
        ci[lvl], ct[lvl], di[lvl], dt[lvl], H, H, scale, (lvl < 2) ? 1 : 0, acc);
  }

  finalize_kernel<<<1, 1, 0, stream>>>(acc, out);
}

// Round 6
// 388.520 us; speedup vs baseline: 6.1799x; 1.0009x over previous
//
#include <hip/hip_runtime.h>

// Laplacian pyramid loss, 3 levels, B*C = 48 channels of 512x512 f32.
// One fused kernel per level: stage cur + horizontal-gauss (via shuffles) ->
// vertical gauss -> down (write owned 16x16 chunk) -> vertical up -> horizontal
// up + diff in LDS -> 3x3 Sobel miniloss |in-tg| -> block reduce -> atomic.
// Gaussian = outer([1,4,6,4,1])^2/256; up weights per axis: even {.125,.75,.125},
// odd {.5,.5} on the decimated grid (reflect on the full grid).

#define NCH 48

__device__ __forceinline__ int refl(int p, int n) {
  // jnp reflect (no edge repeat); valid for p >= -(n-1), p <= 2n-2
  return p < 0 ? -p : (p >= n ? 2 * n - 2 - p : p);
}

__global__ __launch_bounds__(256) void lap_fused_kernel(
    const float* __restrict__ cur_in, const float* __restrict__ cur_tg,
    float* __restrict__ down_in, float* __restrict__ down_tg,
    int H, int W, float scale, int write_down, double* __restrict__ acc)
{
  const int HO = H + 2;
  const int H2 = H >> 1, W2 = W >> 1;
  const int n = blockIdx.z;
  const int bx = blockIdx.x, by = blockIdx.y;
  const int x0 = bx * 32, y0 = by * 32;
  const int tid = threadIdx.x;

  // s_diff: diff window rows y0-2..y0+33 (36), cols x0-8..x0+39 (48)
  __shared__ __align__(16) float s_diff[2][36][48];   // 13.8 KB
  __shared__ __align__(16) float s_hb[2][43][24];     //  8.3 KB (aliased as s_tmp)
  __shared__ __align__(16) float s_down[2][20][24];   //  3.8 KB
  float (*s_tmp)[36][24] = reinterpret_cast<float (*)[36][24]>(&s_hb[0][0][0]);

  const float* curp[2] = {cur_in + (size_t)n * H * W, cur_tg + (size_t)n * H * W};
  float* dwp[2] = {down_in + (size_t)n * H2 * W2, down_tg + (size_t)n * H2 * W2};

  const bool fast = (x0 >= 12) && (x0 + 52 <= W) && (y0 >= 6) && (y0 + 37 <= H);

  const int y_end = min(HO, y0 + 32), x_end = min(HO, x0 + 32);
  int rlo = max(0, y0 - 2);
  if (y_end > H) rlo = min(rlo, 2 * H - 1 - y_end);
  int clo = max(0, x0 - 2);
  if (x_end > W) clo = min(clo, 2 * W - 1 - x_end);
  const int nrows = min(H, y_end) - rlo;
  const int ncols = min(W, x_end) - clo;

  const int dr0 = fast ? (y0 >> 1) - 2 : (max(0, rlo - 2) >> 1);
  const int du0 = fast ? (x0 >> 1) - 4 : (max(0, clo - 2) >> 1);

  // ---- phase A: stage + horizontal gauss ----
  if (fast) {
    const int r0 = y0 - 6, c0 = x0 - 12;   // staged cur rows r0..r0+42, cols c0..c0+63
    const int c4 = tid & 15;               // lane-constant column group
#pragma unroll
    for (int it = 0; it < 6; ++it) {
      int t = tid + it * 256;
      int ri = t >> 4;                     // [0,96)
      int img = ri >= 48;
      int r = ri - (img ? 48 : 0);         // [0,48), valid < 43
      int rc = min(r, 42);
      const float4* src = reinterpret_cast<const float4*>(
          curp[img] + (size_t)(r0 + rc) * W + c0);
      float4 v = src[c4];
      float pz = __shfl_up(v.z, 1);
      float pw = __shfl_up(v.w, 1);
      float nx = __shfl_down(v.x, 1);
      if (r < 43 && c4 >= 1 && c4 <= 12) {
        // centers at cols c0+4*c4 and c0+4*c4+2 -> down cols 2*c4-2, 2*c4-1
        float hb0 = pz + 4.f * pw + 6.f * v.x + 4.f * v.y + v.z;
        float hb1 = v.x + 4.f * v.y + 6.f * v.z + 4.f * v.w + nx;
        *reinterpret_cast<float2*>(&s_hb[img][r][2 * c4 - 2]) = make_float2(hb0, hb1);
        if (r >= 4 && r < 40)
          *reinterpret_cast<float4*>(&s_diff[img][r - 4][4 * (c4 - 1)]) = v;
      }
    }
  } else {
    // diff window: rows rlo..rlo+nrows-1, cols clo..clo+ncols-1 (all interior)
    for (int t = tid; t < 2 * 34 * 36; t += 256) {
      int img = t / 1224, j = t - 1224 * img;
      int l = j / 36, c = j - 36 * l;
      if (l < nrows && c < ncols)
        s_diff[img][l][c] = curp[img][(size_t)(rlo + l) * W + (clo + c)];
    }
    // hb rows 2*dr0-2 .. 2*dr0+40 (reflected), down cols du0..du0+23
    const int r0 = 2 * dr0 - 2;
    for (int t = tid; t < 2 * 43 * 24; t += 256) {
      int img = t / 1032, j = t - 1032 * img;
      int r = j / 24, d = j - 24 * r;
      const float* cp = curp[img];
      size_t rowoff = (size_t)refl(r0 + r, H) * W;
      int m = 2 * (du0 + d);
      s_hb[img][r][d] = cp[rowoff + refl(m - 2, W)] + 4.f * cp[rowoff + refl(m - 1, W)]
                      + 6.f * cp[rowoff + refl(m, W)] + 4.f * cp[rowoff + refl(m + 1, W)]
                      + cp[rowoff + refl(m + 2, W)];
    }
  }
  __syncthreads();

  // ---- phase C: vertical gauss -> s_down (rows dr0..dr0+19) ----
  for (int t = tid; t < 2 * 20 * 24; t += 256) {
    int img = t / 480, j = t - 480 * img;
    int k = j / 24, d = j - 24 * k;
    s_down[img][k][d] = (s_hb[img][2 * k][d] + s_hb[img][2 * k + 4][d]
                       + 6.f * s_hb[img][2 * k + 2][d]
                       + 4.f * (s_hb[img][2 * k + 1][d] + s_hb[img][2 * k + 3][d]))
                      * (1.f / 256.f);
  }
  __syncthreads();

  // ---- phase W: write owned (disjoint) 16x16 chunk of down ----
  if (write_down) {
#pragma unroll
    for (int t = tid; t < 512; t += 256) {
      int img = t >> 8, k = (t & 255) >> 4, c = t & 15;
      int row = 16 * by + k, col = 16 * bx + c;
      if (row < H2 && col < W2)
        dwp[img][(size_t)row * W2 + col] = s_down[img][row - dr0][col - du0];
    }
  }

  // ---- phase D: vertical up-pass -> s_tmp rows 0..35 (aliases s_hb) ----
  if (fast) {
    for (int t = tid; t < 432; t += 256) {
      int img = t / 216, j = t - 216 * img;
      int l = j / 6, c4 = j - 6 * l;
      int rr = (l + (l & 1)) >> 1;
      float4 a = *reinterpret_cast<const float4*>(&s_down[img][rr][4 * c4]);
      float4 b = *reinterpret_cast<const float4*>(&s_down[img][rr + 1][4 * c4]);
      float4 o;
      if (l & 1) {
        o.x = 0.5f * (a.x + b.x);
        o.y = 0.5f * (a.y + b.y);
        o.z = 0.5f * (a.z + b.z);
        o.w = 0.5f * (a.w + b.w);
      } else {
        float4 cc = *reinterpret_cast<const float4*>(&s_down[img][rr + 2][4 * c4]);
        o.x = 0.125f * (a.x + cc.x) + 0.75f * b.x;
        o.y = 0.125f * (a.y + cc.y) + 0.75f * b.y;
        o.z = 0.125f * (a.z + cc.z) + 0.75f * b.z;
        o.w = 0.125f * (a.w + cc.w) + 0.75f * b.w;
      }
      *reinterpret_cast<float4*>(&s_tmp[img][l][4 * c4]) = o;
    }
  } else {
    for (int t = tid; t < 2 * 34 * 24; t += 256) {
      int img = t / 816, j = t - 816 * img;
      int l = j / 24, du = j - 24 * l;
      int p = min(rlo + l, H - 1);
      int ur = min(du, W2 - 1 - du0);
      int par = p & 1;
      int f = p - 2 + par;
      int t0 = (refl(f, H) >> 1) - dr0;
      int t1 = (refl(f + 2, H) >> 1) - dr0;
      int t2 = (refl(f + 4, H) >> 1) - dr0;
      float w0v = par ? 0.5f : 0.125f;
      float w1v = par ? 0.5f : 0.75f;
      float w2v = par ? 0.0f : 0.125f;
      s_tmp[img][l][du] = w0v * s_down[img][t0][ur] + w1v * s_down[img][t1][ur]
                        + w2v * s_down[img][t2][ur];
    }
  }
  __syncthreads();

  // ---- phase E: horizontal up + diff in place over s_diff ----
  if (fast) {
    for (int t = tid; t < 720; t += 256) {
      int img = t / 360, j = t - 360 * img;
      int l = j / 10, c4 = j - 10 * l;
      float4 c = *reinterpret_cast<const float4*>(&s_diff[img][l][4 * c4 + 4]);
      const float* st = s_tmp[img][l];
      float Tm1 = st[2 * c4 + 1], T0 = st[2 * c4 + 2], T1 = st[2 * c4 + 3], T2 = st[2 * c4 + 4];
      float4 d;
      d.x = c.x - (0.125f * (Tm1 + T1) + 0.75f * T0);
      d.y = c.y - 0.5f * (T0 + T1);
      d.z = c.z - (0.125f * (T0 + T2) + 0.75f * T1);
      d.w = c.w - 0.5f * (T1 + T2);
      *reinterpret_cast<float4*>(&s_diff[img][l][4 * c4 + 4]) = d;
    }
  } else {
    for (int t = tid; t < 2448; t += 256) {
      int img = t / 1224, j = t - 1224 * img;
      int l = j / 36, cc = j - 36 * l;
      if (l < nrows && cc < ncols) {
        int q = clo + cc;
        int par = q & 1;
        int f = q - 2 + par;
        int tA = (refl(f, W) >> 1) - du0;
        int tB = (refl(f + 2, W) >> 1) - du0;
        int tC = (refl(f + 4, W) >> 1) - du0;
        float w0v = par ? 0.5f : 0.125f;
        float w1v = par ? 0.5f : 0.75f;
        float w2v = par ? 0.0f : 0.125f;
        float up = w0v * s_tmp[img][l][tA] + w1v * s_tmp[img][l][tB]
                 + w2v * s_tmp[img][l][tC];
        s_diff[img][l][cc] -= up;
      }
    }
  }
  __syncthreads();

  // ---- phase F: 3x3 |gx|+|gy| miniloss, |in - tg| ----
  float val = 0.f;
  if (fast) {
    const int tx = tid & 7, ty = tid >> 3;   // outputs (y0+ty, x0+4*tx..+3)
    float ab[2][4];
#pragma unroll
    for (int img = 0; img < 2; ++img) {
      float a[3][6];
#pragma unroll
      for (int r = 0; r < 3; ++r) {
        const float* row = s_diff[img][ty + r];
        float4 M = *reinterpret_cast<const float4*>(&row[4 * tx + 4]);
        float4 R = *reinterpret_cast<const float4*>(&row[4 * tx + 8]);
        a[r][0] = M.z; a[r][1] = M.w; a[r][2] = R.x;
        a[r][3] = R.y; a[r][4] = R.z; a[r][5] = R.w;
      }
#pragma unroll
      for (int jj = 0; jj < 4; ++jj) {
        float tA = a[0][jj] - a[0][jj + 2];
        float tB = a[1][jj] - a[1][jj + 2];
        float tC = a[2][jj] - a[2][jj + 2];
        float gx = 2.f * (tA + tC) + 4.f * tB;
        float SA = 2.f * (a[0][jj] + a[0][jj + 2]) + 4.f * a[0][jj + 1];
        float SC = 2.f * (a[2][jj] + a[2][jj + 2]) + 4.f * a[2][jj + 1];
        ab[img][jj] = fabsf(gx) + fabsf(SA - SC);
      }
    }
#pragma unroll
    for (int jj = 0; jj < 4; ++jj) val += fabsf(ab[0][jj] - ab[1][jj]);
  } else {
    const int tx = tid & 31, tg8 = tid >> 5;
    const int xx = x0 + tx;
    if (xx < x_end) {
      const int cj0 = refl(xx - 2, W) - clo;
      const int cj1 = refl(xx - 1, W) - clo;
      const int cj2 = refl(xx, W) - clo;
      for (int k = 0; k < 4; ++k) {
        int yy = y0 + 4 * tg8 + k;
        if (yy >= y_end) break;
        int ri0 = refl(yy - 2, H) - rlo;
        int ri1 = refl(yy - 1, H) - rlo;
        int ri2 = refl(yy, H) - rlo;
        float ab2[2];
#pragma unroll
        for (int img = 0; img < 2; ++img) {
          float d00 = s_diff[img][ri0][cj0], d01 = s_diff[img][ri0][cj1], d02 = s_diff[img][ri0][cj2];
          float d10 = s_diff[img][ri1][cj0],                               d12 = s_diff[img][ri1][cj2];
          float d20 = s_diff[img][ri2][cj0], d21 = s_diff[img][ri2][cj1], d22 = s_diff[img][ri2][cj2];
          float gx = 2.f * (d00 - d02) + 4.f * (d10 - d12) + 2.f * (d20 - d22);
          float gy = 2.f * d00 + 4.f * d01 + 2.f * d02 - 2.f * d20 - 4.f * d21 - 2.f * d22;
          ab2[img] = fabsf(gx) + fabsf(gy);
        }
        val += fabsf(ab2[0] - ab2[1]);
      }
    }
  }
  val *= scale;

  // ---- reduction: 256 threads = 4 waves ----
#pragma unroll
  for (int off = 32; off > 0; off >>= 1) val += __shfl_down(val, off, 64);
  __shared__ float wpart[4];
  if ((tid & 63) == 0) wpart[tid >> 6] = val;
  __syncthreads();
  if (tid == 0) atomicAdd(acc, (double)(wpart[0] + wpart[1] + wpart[2] + wpart[3]));
}

__global__ void finalize_kernel(const double* __restrict__ acc, float* __restrict__ out)
{
  out[0] = (float)acc[0];
}

extern "C" void kernel_launch(void* const* d_in, const int* in_sizes, int n_in,
                              void* d_out, int out_size, void* d_ws, size_t ws_size,
                              hipStream_t stream) {
  const float* in = (const float*)d_in[0];
  const float* tg = (const float*)d_in[1];
  float* out = (float*)d_out;

  double* acc = (double*)d_ws;
  float* base = (float*)((char*)d_ws + 16);
  const size_t s0 = (size_t)NCH * 256 * 256;
  const size_t s1 = (size_t)NCH * 128 * 128;
  float* d0i = base;
  float* d0t = d0i + s0;
  float* d1i = d0t + s0;
  float* d1t = d1i + s1;

  hipMemsetAsync(d_ws, 0, 16, stream);

  const float* ci[3] = {in, d0i, d1i};
  const float* ct[3] = {tg, d0t, d1t};
  float* di[3] = {d0i, d1i, d1i};   // level 2 down unused (write_down=0)
  float* dt[3] = {d0t, d1t, d1t};

  for (int lvl = 0; lvl < 3; ++lvl) {
    int H = 512 >> lvl;
    int HO = H + 2;
    int T = (HO + 31) / 32;
    dim3 grid(T, T, NCH);
    float scale = 1.f / ((float)NCH * HO * HO);
    lap_fused_kernel<<<grid, dim3(256), 0, stream>>>(
        ci[lvl], ct[lvl], di[lvl], dt[lvl], H, H, scale, (lvl < 2) ? 1 : 0, acc);
  }

  finalize_kernel<<<1, 1, 0, stream>>>(acc, out);
}

// Round 7
// 312.648 us; speedup vs baseline: 7.6796x; 1.2427x over previous
//
#include <hip/hip_runtime.h>

// Laplacian pyramid loss, 3 levels, B*C = 48 channels of 512x512 f32.
// One fused kernel per level (stage+hgauss via shuffles -> vgauss -> down write
// -> vert up -> horiz up + diff -> Sobel miniloss -> block reduce).
// R7 change: block partial sums go to a per-block slot (no global f64 atomic —
// 18,960 same-address CAS atomics were the suspected ~320us floor); a single
// finalize block tree-reduces the partials.

#define NCH 48

__device__ __forceinline__ int refl(int p, int n) {
  return p < 0 ? -p : (p >= n ? 2 * n - 2 - p : p);
}

__global__ __launch_bounds__(256) void lap_fused_kernel(
    const float* __restrict__ cur_in, const float* __restrict__ cur_tg,
    float* __restrict__ down_in, float* __restrict__ down_tg,
    int H, int W, float scale, int write_down,
    double* __restrict__ partials, int part_off)
{
  const int HO = H + 2;
  const int H2 = H >> 1, W2 = W >> 1;
  const int n = blockIdx.z;
  const int bx = blockIdx.x, by = blockIdx.y;
  const int x0 = bx * 32, y0 = by * 32;
  const int tid = threadIdx.x;

  __shared__ __align__(16) float s_diff[2][36][48];
  __shared__ __align__(16) float s_hb[2][43][24];
  __shared__ __align__(16) float s_down[2][20][24];
  float (*s_tmp)[36][24] = reinterpret_cast<float (*)[36][24]>(&s_hb[0][0][0]);

  const float* curp[2] = {cur_in + (size_t)n * H * W, cur_tg + (size_t)n * H * W};
  float* dwp[2] = {down_in + (size_t)n * H2 * W2, down_tg + (size_t)n * H2 * W2};

  const bool fast = (x0 >= 12) && (x0 + 52 <= W) && (y0 >= 6) && (y0 + 37 <= H);

  const int y_end = min(HO, y0 + 32), x_end = min(HO, x0 + 32);
  int rlo = max(0, y0 - 2);
  if (y_end > H) rlo = min(rlo, 2 * H - 1 - y_end);
  int clo = max(0, x0 - 2);
  if (x_end > W) clo = min(clo, 2 * W - 1 - x_end);
  const int nrows = min(H, y_end) - rlo;
  const int ncols = min(W, x_end) - clo;

  const int dr0 = fast ? (y0 >> 1) - 2 : (max(0, rlo - 2) >> 1);
  const int du0 = fast ? (x0 >> 1) - 4 : (max(0, clo - 2) >> 1);

  // ---- phase A: stage + horizontal gauss ----
  if (fast) {
    const int r0 = y0 - 6, c0 = x0 - 12;
    const int c4 = tid & 15;
#pragma unroll
    for (int it = 0; it < 6; ++it) {
      int t = tid + it * 256;
      int ri = t >> 4;
      int img = ri >= 48;
      int r = ri - (img ? 48 : 0);
      int rc = min(r, 42);
      const float4* src = reinterpret_cast<const float4*>(
          curp[img] + (size_t)(r0 + rc) * W + c0);
      float4 v = src[c4];
      float pz = __shfl_up(v.z, 1);
      float pw = __shfl_up(v.w, 1);
      float nx = __shfl_down(v.x, 1);
      if (r < 43 && c4 >= 1 && c4 <= 12) {
        float hb0 = pz + 4.f * pw + 6.f * v.x + 4.f * v.y + v.z;
        float hb1 = v.x + 4.f * v.y + 6.f * v.z + 4.f * v.w + nx;
        *reinterpret_cast<float2*>(&s_hb[img][r][2 * c4 - 2]) = make_float2(hb0, hb1);
        if (r >= 4 && r < 40)
          *reinterpret_cast<float4*>(&s_diff[img][r - 4][4 * (c4 - 1)]) = v;
      }
    }
  } else {
    for (int t = tid; t < 2 * 34 * 36; t += 256) {
      int img = t / 1224, j = t - 1224 * img;
      int l = j / 36, c = j - 36 * l;
      if (l < nrows && c < ncols)
        s_diff[img][l][c] = curp[img][(size_t)(rlo + l) * W + (clo + c)];
    }
    const int r0 = 2 * dr0 - 2;
    for (int t = tid; t < 2 * 43 * 24; t += 256) {
      int img = t / 1032, j = t - 1032 * img;
      int r = j / 24, d = j - 24 * r;
      const float* cp = curp[img];
      size_t rowoff = (size_t)refl(r0 + r, H) * W;
      int m = 2 * (du0 + d);
      s_hb[img][r][d] = cp[rowoff + refl(m - 2, W)] + 4.f * cp[rowoff + refl(m - 1, W)]
                      + 6.f * cp[rowoff + refl(m, W)] + 4.f * cp[rowoff + refl(m + 1, W)]
                      + cp[rowoff + refl(m + 2, W)];
    }
  }
  __syncthreads();

  // ---- phase C: vertical gauss -> s_down ----
  for (int t = tid; t < 2 * 20 * 24; t += 256) {
    int img = t / 480, j = t - 480 * img;
    int k = j / 24, d = j - 24 * k;
    s_down[img][k][d] = (s_hb[img][2 * k][d] + s_hb[img][2 * k + 4][d]
                       + 6.f * s_hb[img][2 * k + 2][d]
                       + 4.f * (s_hb[img][2 * k + 1][d] + s_hb[img][2 * k + 3][d]))
                      * (1.f / 256.f);
  }
  __syncthreads();

  // ---- phase W: write owned (disjoint) 16x16 chunk of down ----
  if (write_down) {
#pragma unroll
    for (int t = tid; t < 512; t += 256) {
      int img = t >> 8, k = (t & 255) >> 4, c = t & 15;
      int row = 16 * by + k, col = 16 * bx + c;
      if (row < H2 && col < W2)
        dwp[img][(size_t)row * W2 + col] = s_down[img][row - dr0][col - du0];
    }
  }

  // ---- phase D: vertical up-pass -> s_tmp ----
  if (fast) {
    for (int t = tid; t < 432; t += 256) {
      int img = t / 216, j = t - 216 * img;
      int l = j / 6, c4 = j - 6 * l;
      int rr = (l + (l & 1)) >> 1;
      float4 a = *reinterpret_cast<const float4*>(&s_down[img][rr][4 * c4]);
      float4 b = *reinterpret_cast<const float4*>(&s_down[img][rr + 1][4 * c4]);
      float4 o;
      if (l & 1) {
        o.x = 0.5f * (a.x + b.x);
        o.y = 0.5f * (a.y + b.y);
        o.z = 0.5f * (a.z + b.z);
        o.w = 0.5f * (a.w + b.w);
      } else {
        float4 cc = *reinterpret_cast<const float4*>(&s_down[img][rr + 2][4 * c4]);
        o.x = 0.125f * (a.x + cc.x) + 0.75f * b.x;
        o.y = 0.125f * (a.y + cc.y) + 0.75f * b.y;
        o.z = 0.125f * (a.z + cc.z) + 0.75f * b.z;
        o.w = 0.125f * (a.w + cc.w) + 0.75f * b.w;
      }
      *reinterpret_cast<float4*>(&s_tmp[img][l][4 * c4]) = o;
    }
  } else {
    for (int t = tid; t < 2 * 34 * 24; t += 256) {
      int img = t / 816, j = t - 816 * img;
      int l = j / 24, du = j - 24 * l;
      int p = min(rlo + l, H - 1);
      int ur = min(du, W2 - 1 - du0);
      int par = p & 1;
      int f = p - 2 + par;
      int t0 = (refl(f, H) >> 1) - dr0;
      int t1 = (refl(f + 2, H) >> 1) - dr0;
      int t2 = (refl(f + 4, H) >> 1) - dr0;
      float w0v = par ? 0.5f : 0.125f;
      float w1v = par ? 0.5f : 0.75f;
      float w2v = par ? 0.0f : 0.125f;
      s_tmp[img][l][du] = w0v * s_down[img][t0][ur] + w1v * s_down[img][t1][ur]
                        + w2v * s_down[img][t2][ur];
    }
  }
  __syncthreads();

  // ---- phase E: horizontal up + diff in place over s_diff ----
  if (fast) {
    for (int t = tid; t < 720; t += 256) {
      int img = t / 360, j = t - 360 * img;
      int l = j / 10, c4 = j - 10 * l;
      float4 c = *reinterpret_cast<const float4*>(&s_diff[img][l][4 * c4 + 4]);
      const float* st = s_tmp[img][l];
      float Tm1 = st[2 * c4 + 1], T0 = st[2 * c4 + 2], T1 = st[2 * c4 + 3], T2 = st[2 * c4 + 4];
      float4 d;
      d.x = c.x - (0.125f * (Tm1 + T1) + 0.75f * T0);
      d.y = c.y - 0.5f * (T0 + T1);
      d.z = c.z - (0.125f * (T0 + T2) + 0.75f * T1);
      d.w = c.w - 0.5f * (T1 + T2);
      *reinterpret_cast<float4*>(&s_diff[img][l][4 * c4 + 4]) = d;
    }
  } else {
    for (int t = tid; t < 2448; t += 256) {
      int img = t / 1224, j = t - 1224 * img;
      int l = j / 36, cc = j - 36 * l;
      if (l < nrows && cc < ncols) {
        int q = clo + cc;
        int par = q & 1;
        int f = q - 2 + par;
        int tA = (refl(f, W) >> 1) - du0;
        int tB = (refl(f + 2, W) >> 1) - du0;
        int tC = (refl(f + 4, W) >> 1) - du0;
        float w0v = par ? 0.5f : 0.125f;
        float w1v = par ? 0.5f : 0.75f;
        float w2v = par ? 0.0f : 0.125f;
        float up = w0v * s_tmp[img][l][tA] + w1v * s_tmp[img][l][tB]
                 + w2v * s_tmp[img][l][tC];
        s_diff[img][l][cc] -= up;
      }
    }
  }
  __syncthreads();

  // ---- phase F: 3x3 |gx|+|gy| miniloss, |in - tg| ----
  float val = 0.f;
  if (fast) {
    const int tx = tid & 7, ty = tid >> 3;
    float ab[2][4];
#pragma unroll
    for (int img = 0; img < 2; ++img) {
      float a[3][6];
#pragma unroll
      for (int r = 0; r < 3; ++r) {
        const float* row = s_diff[img][ty + r];
        float4 M = *reinterpret_cast<const float4*>(&row[4 * tx + 4]);
        float4 R = *reinterpret_cast<const float4*>(&row[4 * tx + 8]);
        a[r][0] = M.z; a[r][1] = M.w; a[r][2] = R.x;
        a[r][3] = R.y; a[r][4] = R.z; a[r][5] = R.w;
      }
#pragma unroll
      for (int jj = 0; jj < 4; ++jj) {
        float tA = a[0][jj] - a[0][jj + 2];
        float tB = a[1][jj] - a[1][jj + 2];
        float tC = a[2][jj] - a[2][jj + 2];
        float gx = 2.f * (tA + tC) + 4.f * tB;
        float SA = 2.f * (a[0][jj] + a[0][jj + 2]) + 4.f * a[0][jj + 1];
        float SC = 2.f * (a[2][jj] + a[2][jj + 2]) + 4.f * a[2][jj + 1];
        ab[img][jj] = fabsf(gx) + fabsf(SA - SC);
      }
    }
#pragma unroll
    for (int jj = 0; jj < 4; ++jj) val += fabsf(ab[0][jj] - ab[1][jj]);
  } else {
    const int tx = tid & 31, tg8 = tid >> 5;
    const int xx = x0 + tx;
    if (xx < x_end) {
      const int cj0 = refl(xx - 2, W) - clo;
      const int cj1 = refl(xx - 1, W) - clo;
      const int cj2 = refl(xx, W) - clo;
      for (int k = 0; k < 4; ++k) {
        int yy = y0 + 4 * tg8 + k;
        if (yy >= y_end) break;
        int ri0 = refl(yy - 2, H) - rlo;
        int ri1 = refl(yy - 1, H) - rlo;
        int ri2 = refl(yy, H) - rlo;
        float ab2[2];
#pragma unroll
        for (int img = 0; img < 2; ++img) {
          float d00 = s_diff[img][ri0][cj0], d01 = s_diff[img][ri0][cj1], d02 = s_diff[img][ri0][cj2];
          float d10 = s_diff[img][ri1][cj0],                               d12 = s_diff[img][ri1][cj2];
          float d20 = s_diff[img][ri2][cj0], d21 = s_diff[img][ri2][cj1], d22 = s_diff[img][ri2][cj2];
          float gx = 2.f * (d00 - d02) + 4.f * (d10 - d12) + 2.f * (d20 - d22);
          float gy = 2.f * d00 + 4.f * d01 + 2.f * d02 - 2.f * d20 - 4.f * d21 - 2.f * d22;
          ab2[img] = fabsf(gx) + fabsf(gy);
        }
        val += fabsf(ab2[0] - ab2[1]);
      }
    }
  }
  val *= scale;

  // ---- reduction: 4 waves -> one partial slot per block (NO global atomic) ----
#pragma unroll
  for (int off = 32; off > 0; off >>= 1) val += __shfl_down(val, off, 64);
  __shared__ float wpart[4];
  if ((tid & 63) == 0) wpart[tid >> 6] = val;
  __syncthreads();
  if (tid == 0) {
    double s = (double)wpart[0] + (double)wpart[1] + (double)wpart[2] + (double)wpart[3];
    int lin = (blockIdx.z * gridDim.y + blockIdx.y) * gridDim.x + blockIdx.x;
    partials[part_off + lin] = s;
  }
}

__global__ __launch_bounds__(1024) void finalize_kernel(
    const double* __restrict__ partials, int N, float* __restrict__ out)
{
  double s = 0.0;
  for (int i = threadIdx.x; i < N; i += 1024) s += partials[i];
#pragma unroll
  for (int off = 32; off > 0; off >>= 1)
    s += __shfl_down(s, off, 64);
  __shared__ double wp[16];
  if ((threadIdx.x & 63) == 0) wp[threadIdx.x >> 6] = s;
  __syncthreads();
  if (threadIdx.x == 0) {
    double t = 0.0;
#pragma unroll
    for (int i = 0; i < 16; ++i) t += wp[i];
    out[0] = (float)t;
  }
}

extern "C" void kernel_launch(void* const* d_in, const int* in_sizes, int n_in,
                              void* d_out, int out_size, void* d_ws, size_t ws_size,
                              hipStream_t stream) {
  const float* in = (const float*)d_in[0];
  const float* tg = (const float*)d_in[1];
  float* out = (float*)d_out;

  // grids: L0 17x17x48=13872, L1 9x9x48=3888, L2 5x5x48=1200 -> 18960 partials
  const int NPART = 18960;
  double* partials = (double*)d_ws;
  float* base = (float*)((char*)d_ws + (size_t)NPART * sizeof(double));
  const size_t s0 = (size_t)NCH * 256 * 256;
  const size_t s1 = (size_t)NCH * 128 * 128;
  float* d0i = base;
  float* d0t = d0i + s0;
  float* d1i = d0t + s0;
  float* d1t = d1i + s1;

  const float* ci[3] = {in, d0i, d1i};
  const float* ct[3] = {tg, d0t, d1t};
  float* di[3] = {d0i, d1i, d1i};
  float* dt[3] = {d0t, d1t, d1t};

  int part_off = 0;
  for (int lvl = 0; lvl < 3; ++lvl) {
    int H = 512 >> lvl;
    int HO = H + 2;
    int T = (HO + 31) / 32;
    dim3 grid(T, T, NCH);
    float scale = 1.f / ((float)NCH * HO * HO);
    lap_fused_kernel<<<grid, dim3(256), 0, stream>>>(
        ci[lvl], ct[lvl], di[lvl], dt[lvl], H, H, scale, (lvl < 2) ? 1 : 0,
        partials, part_off);
    part_off += T * T * NCH;
  }

  finalize_kernel<<<1, dim3(1024), 0, stream>>>(partials, NPART, out);
}

// Round 8
// 297.146 us; speedup vs baseline: 8.0802x; 1.0522x over previous
//
#include <hip/hip_runtime.h>

// Laplacian pyramid loss, 3 levels, B*C = 48 channels of 512x512 f32.
// One fused kernel per level. R8: vectorized edge-path staging via LDS s_cur
// (row-reflect + col-clamp float4 loads; reflect resolved as LDS re-index),
// fast staging trimmed to 14 float4 groups, phase C vectorized.

#define NCH 48

__device__ __forceinline__ int refl(int p, int n) {
  return p < 0 ? -p : (p >= n ? 2 * n - 2 - p : p);
}

__global__ __launch_bounds__(256) void lap_fused_kernel(
    const float* __restrict__ cur_in, const float* __restrict__ cur_tg,
    float* __restrict__ down_in, float* __restrict__ down_tg,
    int H, int W, float scale, int write_down,
    double* __restrict__ partials, int part_off)
{
  const int HO = H + 2;
  const int H2 = H >> 1, W2 = W >> 1;
  const int n = blockIdx.z;
  const int bx = blockIdx.x, by = blockIdx.y;
  const int x0 = bx * 32, y0 = by * 32;
  const int tid = threadIdx.x;

  __shared__ __align__(16) float s_diff[2][36][48];   // 13.8 KB
  __shared__ __align__(16) float s_hb[2][43][24];     //  8.3 KB (aliased as s_tmp)
  __shared__ __align__(16) float s_cd[2408];          //  9.6 KB: edge s_cur[43][56] / s_down[2][20][24]
  float (*s_tmp)[36][24] = reinterpret_cast<float (*)[36][24]>(&s_hb[0][0][0]);
  float (*s_down)[20][24] = reinterpret_cast<float (*)[20][24]>(&s_cd[0]);
  float (*s_cur)[56] = reinterpret_cast<float (*)[56]>(&s_cd[0]);

  const float* curp[2] = {cur_in + (size_t)n * H * W, cur_tg + (size_t)n * H * W};
  float* dwp[2] = {down_in + (size_t)n * H2 * W2, down_tg + (size_t)n * H2 * W2};

  const bool fast = (x0 >= 12) && (x0 + 52 <= W) && (y0 >= 6) && (y0 + 37 <= H);

  const int y_end = min(HO, y0 + 32), x_end = min(HO, x0 + 32);
  int rlo = max(0, y0 - 2);
  if (y_end > H) rlo = min(rlo, 2 * H - 1 - y_end);
  int clo = max(0, x0 - 2);
  if (x_end > W) clo = min(clo, 2 * W - 1 - x_end);
  const int nrows = min(H, y_end) - rlo;
  const int ncols = min(W, x_end) - clo;

  const int dr0 = fast ? (y0 >> 1) - 2 : (max(0, rlo - 2) >> 1);
  const int du0 = fast ? (x0 >> 1) - 4 : (max(0, clo - 2) >> 1);
  const int r0 = 2 * dr0 - 2;   // abs row of staged row 0 (hb/s_cur space)

  // ---- phase A: stage + horizontal gauss ----
  if (fast) {
    const int c0 = x0 - 12;     // = 2*du0 - 4, float4-aligned
#pragma unroll
    for (int it = 0; it < 5; ++it) {
      int t = tid + it * 256;
      if (t < 1204) {                       // 2 img * 43 rows * 14 groups
        int ri = t / 14;
        int c4 = t - 14 * ri;
        int img = ri >= 43;
        int r = ri - (img ? 43 : 0);
        const float4* src = reinterpret_cast<const float4*>(
            curp[img] + (size_t)(r0 + r) * W + c0);
        float4 v = src[c4];
        float pz = __shfl_up(v.z, 1);
        float pw = __shfl_up(v.w, 1);
        float nx = __shfl_down(v.x, 1);
        if (c4 >= 1 && c4 <= 12) {
          float hb0 = pz + 4.f * pw + 6.f * v.x + 4.f * v.y + v.z;
          float hb1 = v.x + 4.f * v.y + 6.f * v.z + 4.f * v.w + nx;
          *reinterpret_cast<float2*>(&s_hb[img][r][2 * c4 - 2]) = make_float2(hb0, hb1);
          if (r >= 4 && r < 40)
            *reinterpret_cast<float4*>(&s_diff[img][r - 4][4 * (c4 - 1)]) = v;
        }
      }
    }
  } else {
    // vectorized edge staging: per image, s_cur <- row-reflected float4 rows,
    // then hb + diff-window from LDS with reflected local column indices.
    const int S0a = max(0, 2 * du0 - 2) & ~3;   // staged col 0 (aligned)
    const int dmax = W2 - 1 - du0;              // last used down col (rel)
    for (int im = 0; im < 2; ++im) {
      for (int t = tid; t < 602; t += 256) {    // 43 rows * 14 groups
        int r = t / 14, c4 = t - 14 * r;
        int gr = refl(r0 + r, H);
        int gb = min(S0a + 4 * c4, W - 4);
        *reinterpret_cast<float4*>(&s_cur[r][4 * c4]) =
            *reinterpret_cast<const float4*>(curp[im] + (size_t)gr * W + gb);
      }
      __syncthreads();
      for (int t = tid; t < 1032; t += 256) {   // 43 rows * 24 down cols
        int r = t / 24, d = t - 24 * r;
        int de = min(d, dmax);
        int m = 2 * (du0 + de);
        const float* row = s_cur[r];
        s_hb[im][r][d] = row[refl(m - 2, W) - S0a] + 4.f * row[refl(m - 1, W) - S0a]
                       + 6.f * row[refl(m, W) - S0a] + 4.f * row[refl(m + 1, W) - S0a]
                       + row[refl(m + 2, W) - S0a];
      }
      for (int t = tid; t < 1224; t += 256) {   // 34 * 36 diff window
        int l = t / 36, c = t - 36 * l;
        if (l < nrows && c < ncols)
          s_diff[im][l][c] = s_cur[(rlo + l) - r0][(clo + c) - S0a];
      }
      __syncthreads();
    }
  }
  __syncthreads();

  // ---- phase C: vertical gauss -> s_down (float4; overwrites s_cur region) ----
  if (tid < 240) {                              // 2 img * 20 rows * 6 groups
    int img = tid >= 120;
    int j = tid - 120 * img;
    int k = j / 6, c4 = j - 6 * k;
    float4 h0 = *reinterpret_cast<const float4*>(&s_hb[img][2 * k][4 * c4]);
    float4 h1 = *reinterpret_cast<const float4*>(&s_hb[img][2 * k + 1][4 * c4]);
    float4 h2 = *reinterpret_cast<const float4*>(&s_hb[img][2 * k + 2][4 * c4]);
    float4 h3 = *reinterpret_cast<const float4*>(&s_hb[img][2 * k + 3][4 * c4]);
    float4 h4 = *reinterpret_cast<const float4*>(&s_hb[img][2 * k + 4][4 * c4]);
    float4 o;
    o.x = (h0.x + h4.x + 6.f * h2.x + 4.f * (h1.x + h3.x)) * (1.f / 256.f);
    o.y = (h0.y + h4.y + 6.f * h2.y + 4.f * (h1.y + h3.y)) * (1.f / 256.f);
    o.z = (h0.z + h4.z + 6.f * h2.z + 4.f * (h1.z + h3.z)) * (1.f / 256.f);
    o.w = (h0.w + h4.w + 6.f * h2.w + 4.f * (h1.w + h3.w)) * (1.f / 256.f);
    *reinterpret_cast<float4*>(&s_down[img][k][4 * c4]) = o;
  }
  __syncthreads();

  // ---- phase W: write owned (disjoint) 16x16 chunk of down ----
  if (write_down) {
#pragma unroll
    for (int t = tid; t < 512; t += 256) {
      int img = t >> 8, k = (t & 255) >> 4, c = t & 15;
      int row = 16 * by + k, col = 16 * bx + c;
      if (row < H2 && col < W2)
        dwp[img][(size_t)row * W2 + col] = s_down[img][row - dr0][col - du0];
    }
  }

  // ---- phase D: vertical up-pass -> s_tmp (aliases s_hb) ----
  if (fast) {
    for (int t = tid; t < 432; t += 256) {
      int img = t / 216, j = t - 216 * img;
      int l = j / 6, c4 = j - 6 * l;
      int rr = (l + (l & 1)) >> 1;
      float4 a = *reinterpret_cast<const float4*>(&s_down[img][rr][4 * c4]);
      float4 b = *reinterpret_cast<const float4*>(&s_down[img][rr + 1][4 * c4]);
      float4 o;
      if (l & 1) {
        o.x = 0.5f * (a.x + b.x);
        o.y = 0.5f * (a.y + b.y);
        o.z = 0.5f * (a.z + b.z);
        o.w = 0.5f * (a.w + b.w);
      } else {
        float4 cc = *reinterpret_cast<const float4*>(&s_down[img][rr + 2][4 * c4]);
        o.x = 0.125f * (a.x + cc.x) + 0.75f * b.x;
        o.y = 0.125f * (a.y + cc.y) + 0.75f * b.y;
        o.z = 0.125f * (a.z + cc.z) + 0.75f * b.z;
        o.w = 0.125f * (a.w + cc.w) + 0.75f * b.w;
      }
      *reinterpret_cast<float4*>(&s_tmp[img][l][4 * c4]) = o;
    }
  } else {
    for (int t = tid; t < 2 * 34 * 24; t += 256) {
      int img = t / 816, j = t - 816 * img;
      int l = j / 24, du = j - 24 * l;
      int p = min(rlo + l, H - 1);
      int ur = min(du, W2 - 1 - du0);
      int par = p & 1;
      int f = p - 2 + par;
      int t0 = (refl(f, H) >> 1) - dr0;
      int t1 = (refl(f + 2, H) >> 1) - dr0;
      int t2 = (refl(f + 4, H) >> 1) - dr0;
      float w0v = par ? 0.5f : 0.125f;
      float w1v = par ? 0.5f : 0.75f;
      float w2v = par ? 0.0f : 0.125f;
      s_tmp[img][l][du] = w0v * s_down[img][t0][ur] + w1v * s_down[img][t1][ur]
                        + w2v * s_down[img][t2][ur];
    }
  }
  __syncthreads();

  // ---- phase E: horizontal up + diff in place over s_diff ----
  if (fast) {
    for (int t = tid; t < 720; t += 256) {
      int img = t / 360, j = t - 360 * img;
      int l = j / 10, c4 = j - 10 * l;
      float4 c = *reinterpret_cast<const float4*>(&s_diff[img][l][4 * c4 + 4]);
      const float* st = s_tmp[img][l];
      float Tm1 = st[2 * c4 + 1], T0 = st[2 * c4 + 2], T1 = st[2 * c4 + 3], T2 = st[2 * c4 + 4];
      float4 d;
      d.x = c.x - (0.125f * (Tm1 + T1) + 0.75f * T0);
      d.y = c.y - 0.5f * (T0 + T1);
      d.z = c.z - (0.125f * (T0 + T2) + 0.75f * T1);
      d.w = c.w - 0.5f * (T1 + T2);
      *reinterpret_cast<float4*>(&s_diff[img][l][4 * c4 + 4]) = d;
    }
  } else {
    for (int t = tid; t < 2448; t += 256) {
      int img = t / 1224, j = t - 1224 * img;
      int l = j / 36, cc = j - 36 * l;
      if (l < nrows && cc < ncols) {
        int q = clo + cc;
        int par = q & 1;
        int f = q - 2 + par;
        int tA = (refl(f, W) >> 1) - du0;
        int tB = (refl(f + 2, W) >> 1) - du0;
        int tC = (refl(f + 4, W) >> 1) - du0;
        float w0v = par ? 0.5f : 0.125f;
        float w1v = par ? 0.5f : 0.75f;
        float w2v = par ? 0.0f : 0.125f;
        float up = w0v * s_tmp[img][l][tA] + w1v * s_tmp[img][l][tB]
                 + w2v * s_tmp[img][l][tC];
        s_diff[img][l][cc] -= up;
      }
    }
  }
  __syncthreads();

  // ---- phase F: 3x3 |gx|+|gy| miniloss, |in - tg| ----
  float val = 0.f;
  if (fast) {
    const int tx = tid & 7, ty = tid >> 3;
    float ab[2][4];
#pragma unroll
    for (int img = 0; img < 2; ++img) {
      float a[3][6];
#pragma unroll
      for (int r = 0; r < 3; ++r) {
        const float* row = s_diff[img][ty + r];
        float4 M = *reinterpret_cast<const float4*>(&row[4 * tx + 4]);
        float4 R = *reinterpret_cast<const float4*>(&row[4 * tx + 8]);
        a[r][0] = M.z; a[r][1] = M.w; a[r][2] = R.x;
        a[r][3] = R.y; a[r][4] = R.z; a[r][5] = R.w;
      }
#pragma unroll
      for (int jj = 0; jj < 4; ++jj) {
        float tA = a[0][jj] - a[0][jj + 2];
        float tB = a[1][jj] - a[1][jj + 2];
        float tC = a[2][jj] - a[2][jj + 2];
        float gx = 2.f * (tA + tC) + 4.f * tB;
        float SA = 2.f * (a[0][jj] + a[0][jj + 2]) + 4.f * a[0][jj + 1];
        float SC = 2.f * (a[2][jj] + a[2][jj + 2]) + 4.f * a[2][jj + 1];
        ab[img][jj] = fabsf(gx) + fabsf(SA - SC);
      }
    }
#pragma unroll
    for (int jj = 0; jj < 4; ++jj) val += fabsf(ab[0][jj] - ab[1][jj]);
  } else {
    const int tx = tid & 31, tg8 = tid >> 5;
    const int xx = x0 + tx;
    if (xx < x_end) {
      const int cj0 = refl(xx - 2, W) - clo;
      const int cj1 = refl(xx - 1, W) - clo;
      const int cj2 = refl(xx, W) - clo;
      for (int k = 0; k < 4; ++k) {
        int yy = y0 + 4 * tg8 + k;
        if (yy >= y_end) break;
        int ri0 = refl(yy - 2, H) - rlo;
        int ri1 = refl(yy - 1, H) - rlo;
        int ri2 = refl(yy, H) - rlo;
        float ab2[2];
#pragma unroll
        for (int img = 0; img < 2; ++img) {
          float d00 = s_diff[img][ri0][cj0], d01 = s_diff[img][ri0][cj1], d02 = s_diff[img][ri0][cj2];
          float d10 = s_diff[img][ri1][cj0],                               d12 = s_diff[img][ri1][cj2];
          float d20 = s_diff[img][ri2][cj0], d21 = s_diff[img][ri2][cj1], d22 = s_diff[img][ri2][cj2];
          float gx = 2.f * (d00 - d02) + 4.f * (d10 - d12) + 2.f * (d20 - d22);
          float gy = 2.f * d00 + 4.f * d01 + 2.f * d02 - 2.f * d20 - 4.f * d21 - 2.f * d22;
          ab2[img] = fabsf(gx) + fabsf(gy);
        }
        val += fabsf(ab2[0] - ab2[1]);
      }
    }
  }
  val *= scale;

  // ---- reduction -> per-block partial slot ----
#pragma unroll
  for (int off = 32; off > 0; off >>= 1) val += __shfl_down(val, off, 64);
  __shared__ float wpart[4];
  if ((tid & 63) == 0) wpart[tid >> 6] = val;
  __syncthreads();
  if (tid == 0) {
    double s = (double)wpart[0] + (double)wpart[1] + (double)wpart[2] + (double)wpart[3];
    int lin = (blockIdx.z * gridDim.y + blockIdx.y) * gridDim.x + blockIdx.x;
    partials[part_off + lin] = s;
  }
}

__global__ __launch_bounds__(1024) void finalize_kernel(
    const double* __restrict__ partials, int N, float* __restrict__ out)
{
  double s = 0.0;
  for (int i = threadIdx.x; i < N; i += 1024) s += partials[i];
#pragma unroll
  for (int off = 32; off > 0; off >>= 1)
    s += __shfl_down(s, off, 64);
  __shared__ double wp[16];
  if ((threadIdx.x & 63) == 0) wp[threadIdx.x >> 6] = s;
  __syncthreads();
  if (threadIdx.x == 0) {
    double t = 0.0;
#pragma unroll
    for (int i = 0; i < 16; ++i) t += wp[i];
    out[0] = (float)t;
  }
}

extern "C" void kernel_launch(void* const* d_in, const int* in_sizes, int n_in,
                              void* d_out, int out_size, void* d_ws, size_t ws_size,
                              hipStream_t stream) {
  const float* in = (const float*)d_in[0];
  const float* tg = (const float*)d_in[1];
  float* out = (float*)d_out;

  const int NPART = 18960;   // 17*17*48 + 9*9*48 + 5*5*48
  double* partials = (double*)d_ws;
  float* base = (float*)((char*)d_ws + (size_t)NPART * sizeof(double));
  const size_t s0 = (size_t)NCH * 256 * 256;
  const size_t s1 = (size_t)NCH * 128 * 128;
  float* d0i = base;
  float* d0t = d0i + s0;
  float* d1i = d0t + s0;
  float* d1t = d1i + s1;

  const float* ci[3] = {in, d0i, d1i};
  const float* ct[3] = {tg, d0t, d1t};
  float* di[3] = {d0i, d1i, d1i};
  float* dt[3] = {d0t, d1t, d1t};

  int part_off = 0;
  for (int lvl = 0; lvl < 3; ++lvl) {
    int H = 512 >> lvl;
    int HO = H + 2;
    int T = (HO + 31) / 32;
    dim3 grid(T, T, NCH);
    float scale = 1.f / ((float)NCH * HO * HO);
    lap_fused_kernel<<<grid, dim3(256), 0, stream>>>(
        ci[lvl], ct[lvl], di[lvl], dt[lvl], H, H, scale, (lvl < 2) ? 1 : 0,
        partials, part_off);
    part_off += T * T * NCH;
  }

  finalize_kernel<<<1, dim3(1024), 0, stream>>>(partials, NPART, out);
}